// Round 3
// baseline (706.056 us; speedup 1.0000x reference)
//
#include <hip/hip_runtime.h>

#define BATCH 2
#define NPART 32768
#define GD 64
#define NVOX (BATCH * GD * GD * GD)   // 524288

typedef unsigned short ushortT;
typedef __attribute__((ext_vector_type(8))) short short8;
typedef __attribute__((ext_vector_type(16))) float float16;

__device__ __forceinline__ float poly6_c() {
    const double H9 = 1.0 / 35184372088832.0; // 0.03125^9 == 2^-45 (exact)
    return (float)(315.0 / (64.0 * 3.14159265358979323846 * H9));
}

__device__ __forceinline__ ushortT bf16_rne(float f) {
    unsigned int u = __float_as_uint(f);
    u = (u + 0x7fffu + ((u >> 16) & 1u)) >> 16;   // round-to-nearest-even
    return (ushortT)u;
}

// ---------------- zero the 4-channel splat grid ----------------
__global__ void zero_kernel(float4* __restrict__ p, int n4) {
    int t = blockIdx.x * blockDim.x + threadIdx.x;
    if (t < n4) p[t] = float4{0.f, 0.f, 0.f, 0.f};
}

// ---------------- particles2grid (poly6 scatter, fp32) ----------------
// unsafeAtomicAdd -> hardware global_atomic_add_f32 (memory-side, no CAS loop).
__global__ __launch_bounds__(256) void splat_kernel(
    const float* __restrict__ locs, const float* __restrict__ data,
    const float* __restrict__ density, float* __restrict__ grid) {
    int t = blockIdx.x * blockDim.x + threadIdx.x;
    if (t >= BATCH * NPART) return;
    int b = t >> 15;

    float px = locs[t * 3 + 0];
    float py = locs[t * 3 + 1];
    float pz = locs[t * 3 + 2];
    float inv_d = 1.0f / density[t];
    float v0 = data[t * 4 + 0] * inv_d;
    float v1 = data[t * 4 + 1] * inv_d;
    float v2 = data[t * 4 + 2] * inv_d;
    float v3 = data[t * 4 + 3] * inv_d;

    int bx = (int)floorf(px * 64.0f);
    int by = (int)floorf(py * 64.0f);
    int bz = (int)floorf(pz * 64.0f);

    const float step = 0.015625f;
    const float h2 = 0.03125f * 0.03125f;
    const float cc = poly6_c();

    float* gb = grid + (size_t)b * GD * GD * GD * 4;

    for (int dx = -2; dx <= 2; ++dx) {
        int x = bx + dx;
        if ((unsigned)x > 63u) continue;
        float cx = ((float)x + 0.5f) * step - px;
        float dx2 = cx * cx;
        for (int dy = -2; dy <= 2; ++dy) {
            int y = by + dy;
            if ((unsigned)y > 63u) continue;
            float cy = ((float)y + 0.5f) * step - py;
            float dxy2 = dx2 + cy * cy;
            if (dxy2 > h2) continue;
            for (int dz = -2; dz <= 2; ++dz) {
                int z = bz + dz;
                if ((unsigned)z > 63u) continue;
                float cz = ((float)z + 0.5f) * step - pz;
                float d2 = dxy2 + cz * cz;
                if (d2 > h2) continue;
                float u = h2 - d2;
                float w = cc * u * u * u;
                float* gp = gb + (size_t)(((x * GD) + y) * GD + z) * 4;
                unsafeAtomicAdd(gp + 0, w * v0);
                unsafeAtomicAdd(gp + 1, w * v1);
                unsafeAtomicAdd(gp + 2, w * v2);
                unsafeAtomicAdd(gp + 3, w * v3);
            }
        }
    }
}

// ---------------- fp32 4ch grid -> bf16 8ch grid (ch 4..7 = 0) ----------------
__global__ __launch_bounds__(256) void convert_kernel(
    const float4* __restrict__ g4, short8* __restrict__ g8) {
    int t = blockIdx.x * blockDim.x + threadIdx.x;   // NVOX
    float4 v = g4[t];
    short8 o;
    o[0] = (short)bf16_rne(v.x);
    o[1] = (short)bf16_rne(v.y);
    o[2] = (short)bf16_rne(v.z);
    o[3] = (short)bf16_rne(v.w);
    o[4] = 0; o[5] = 0; o[6] = 0; o[7] = 0;
    g8[t] = o;
}

// ---------------- weight repack into MFMA B-fragment order ----------------
// Bpack[kt][lane][j] (bf16), lane: n = l&31, q = l>>5; k = kt*16 + 8q + j
// k = tap*CINP + ic ; valid iff tap<27 && ic<I && n<O
__global__ void repack_kernel(const float* __restrict__ W, short* __restrict__ Bp,
                              int O, int I, int CINP, int KT) {
    int t = blockIdx.x * blockDim.x + threadIdx.x;
    int total = KT * 512;
    if (t >= total) return;
    int kt = t >> 9;
    int l  = (t >> 3) & 63;
    int j  = t & 7;
    int n = l & 31, q = l >> 5;
    int k = kt * 16 + 8 * q + j;
    int tap = k / CINP;
    int ic  = k - tap * CINP;
    float v = 0.f;
    if (tap < 27 && ic < I && n < O) v = W[(n * I + ic) * 27 + tap];
    Bp[t] = (short)bf16_rne(v);
}

// ---------------- MFMA implicit-GEMM 3x3x3 conv ----------------
// in: bf16 [B][64][64][64][ICG*8]; WG = (b,x,ypair): 2 z-columns, 4 waves.
// wave w: ycol = w>>1, M-tile z base mz = (w&1)*32; N = 32 output channels.
template <int ICG, int KT, bool FINAL>
__global__ __launch_bounds__(256) void mfma_conv_kernel(
    const ushortT* __restrict__ in, const short* __restrict__ Bpack,
    const float* __restrict__ bias, const float* __restrict__ alpha,
    void* __restrict__ outv) {
    constexpr int CIN = ICG * 8;
    __shared__ short lds[12 * ICG * 66 * 8];       // [col12][icg][z66][8ch]
    int wg = blockIdx.x;                           // 2*64*32 = 4096
    int yp = wg & 31, x = (wg >> 5) & 63, b = wg >> 11;
    int y0 = yp * 2;
    int tid = threadIdx.x;

    // ---- stage 12-column halo tile into LDS (layout linear in chunk id) ----
    const int NCH = 12 * ICG * 66;                 // 16B chunks
    for (int cc = tid; cc < NCH; cc += 256) {
        int col = cc / (ICG * 66);
        int rem = cc - col * (ICG * 66);
        int icg = rem / 66;
        int z66 = rem - icg * 66;
        int gx = x + (col >> 2) - 1;               // col = dx*4 + ty
        int gy = y0 + (col & 3) - 1;
        int z  = z66 - 1;
        short8 v = short8{0,0,0,0,0,0,0,0};
        if ((unsigned)gx < 64u && (unsigned)gy < 64u && (unsigned)z < 64u)
            v = *(const short8*)(in + ((size_t)(((b * 64 + gx) * 64 + gy) * 64 + z)) * CIN + icg * 8);
        *(short8*)(lds + cc * 8) = v;
    }
    __syncthreads();

    int l = tid & 63, w = tid >> 6;
    int ycol = w >> 1, mz = (w & 1) * 32;
    int n = l & 31, q = l >> 5;

    float bval = FINAL ? (n < 4 ? bias[n] : 0.f) : bias[n];
    float16 acc;
#pragma unroll
    for (int r = 0; r < 16; ++r) acc[r] = bval;

    const short* bp = Bpack + (size_t)l * 8;
    int laneBase = (mz + (l & 31)) * 8;
    int ycolOfs  = ycol * (ICG * 66) * 8;

#pragma unroll
    for (int kt = 0; kt < KT; ++kt) {
        short8 bfrag = *(const short8*)(bp + kt * 512);
        int aofs;
        if constexpr (ICG == 1) {
            int tap0 = kt * 2, tap1 = kt * 2 + 1;
            if (tap1 > 26) tap1 = 26;              // B is zero there; any valid addr
            int dx0 = tap0 / 9, r0 = tap0 - dx0 * 9, dy0 = r0 / 3, dz0 = r0 - dy0 * 3;
            int dx1 = tap1 / 9, r1 = tap1 - dx1 * 9, dy1 = r1 / 3, dz1 = r1 - dy1 * 3;
            int c0 = ((dx0 * 4 + dy0) * 66 + dz0) * 8;
            int c1 = ((dx1 * 4 + dy1) * 66 + dz1) * 8;
            aofs = q ? c1 : c0;
        } else {
            int tap = kt >> 1;
            int dx = tap / 9, rr = tap - dx * 9, dy = rr / 3, dz = rr - dy * 3;
            int icg = (kt & 1) * 2 + q;
            aofs = (((dx * 4 + dy) * ICG + icg) * 66 + dz) * 8;
        }
        short8 afrag = *(const short8*)(lds + aofs + ycolOfs + laneBase);
        acc = __builtin_amdgcn_mfma_f32_32x32x16_bf16(afrag, bfrag, acc, 0, 0, 0);
    }

    int ygl = y0 + ycol;
    size_t base = (size_t)(((b * 64 + x) * 64 + ygl) * 64);
    if (FINAL) {
        float* out = (float*)outv;
        if (n < 4) {
#pragma unroll
            for (int r = 0; r < 16; ++r) {
                int z = mz + (r & 3) + 8 * (r >> 2) + 4 * q;
                out[(base + z) * 4 + n] = acc[r];
            }
        }
    } else {
        float a = alpha[0];
        ushortT* out = (ushortT*)outv;
#pragma unroll
        for (int r = 0; r < 16; ++r) {
            int z = mz + (r & 3) + 8 * (r >> 2) + 4 * q;
            float v = acc[r];
            v = v >= 0.f ? v : a * v;
            out[(base + z) * 32 + n] = bf16_rne(v);
        }
    }
}

// ---------------- grid2particles (trilinear gather, fp32 grid) ----------------
__global__ __launch_bounds__(256) void gather_kernel(
    const float* __restrict__ grid, const float* __restrict__ locs,
    float* __restrict__ out) {
    int t = blockIdx.x * blockDim.x + threadIdx.x;
    if (t >= BATCH * NPART) return;
    int b = t >> 15;

    float px = locs[t * 3 + 0] * 64.0f - 0.5f;
    float py = locs[t * 3 + 1] * 64.0f - 0.5f;
    float pz = locs[t * 3 + 2] * 64.0f - 0.5f;
    int ix = (int)floorf(px);
    int iy = (int)floorf(py);
    int iz = (int)floorf(pz);
    float fx = px - (float)ix;
    float fy = py - (float)iy;
    float fz = pz - (float)iz;

    const float* gb = grid + (size_t)b * GD * GD * GD * 4;
    float o0 = 0.f, o1 = 0.f, o2 = 0.f, o3 = 0.f;

#pragma unroll
    for (int dx = 0; dx < 2; ++dx) {
        int x = ix + dx;
        if ((unsigned)x > 63u) continue;
        float wx = dx ? fx : 1.0f - fx;
#pragma unroll
        for (int dy = 0; dy < 2; ++dy) {
            int y = iy + dy;
            if ((unsigned)y > 63u) continue;
            float wy = dy ? fy : 1.0f - fy;
#pragma unroll
            for (int dz = 0; dz < 2; ++dz) {
                int z = iz + dz;
                if ((unsigned)z > 63u) continue;
                float wz = dz ? fz : 1.0f - fz;
                float w = wx * wy * wz;
                const float4 g = *(const float4*)(gb + (size_t)(((x * GD) + y) * GD + z) * 4);
                o0 += w * g.x; o1 += w * g.y; o2 += w * g.z; o3 += w * g.w;
            }
        }
    }
    out[t * 4 + 0] = o0;
    out[t * 4 + 1] = o1;
    out[t * 4 + 2] = o2;
    out[t * 4 + 3] = o3;
}

extern "C" void kernel_launch(void* const* d_in, const int* in_sizes, int n_in,
                              void* d_out, int out_size, void* d_ws, size_t ws_size,
                              hipStream_t stream) {
    const float* locs    = (const float*)d_in[0];
    const float* data    = (const float*)d_in[1];
    const float* density = (const float*)d_in[2];
    const float* W0 = (const float*)d_in[3];
    const float* b0 = (const float*)d_in[4];
    const float* W1 = (const float*)d_in[5];
    const float* b1 = (const float*)d_in[6];
    const float* W2 = (const float*)d_in[7];
    const float* b2 = (const float*)d_in[8];
    const float* W3 = (const float*)d_in[9];
    const float* b3 = (const float*)d_in[10];
    const float* a0 = (const float*)d_in[11];
    const float* a1 = (const float*)d_in[12];
    const float* a2 = (const float*)d_in[13];
    float* out = (float*)d_out;

    char* ws = (char*)d_ws;
    float*  g4   = (float*)(ws);                         // 8 MB fp32 4ch
    ushortT* g8  = (ushortT*)(ws + 8388608);             // 8 MB bf16 8ch
    ushortT* gA  = (ushortT*)(ws + 16777216);            // 33.5 MB bf16 32ch
    ushortT* gB  = (ushortT*)(ws + 50331648);            // 33.5 MB bf16 32ch
    float*  gF   = (float*)(ws + 83886080);              // 8 MB fp32 4ch
    short*  Bp0  = (short*)(ws + 92274688);              // 14*512*2  = 14336 B
    short*  Bp1  = (short*)(ws + 92291072);              // 54*512*2  = 55296 B
    short*  Bp2  = (short*)(ws + 92346368);
    short*  Bp3  = (short*)(ws + 92401664);

    zero_kernel<<<NVOX / 256, 256, 0, stream>>>((float4*)g4, NVOX);

    repack_kernel<<<(14 * 512 + 255) / 256, 256, 0, stream>>>(W0, Bp0, 32,  4,  8, 14);
    repack_kernel<<<(54 * 512 + 255) / 256, 256, 0, stream>>>(W1, Bp1, 32, 32, 32, 54);
    repack_kernel<<<(54 * 512 + 255) / 256, 256, 0, stream>>>(W2, Bp2, 32, 32, 32, 54);
    repack_kernel<<<(54 * 512 + 255) / 256, 256, 0, stream>>>(W3, Bp3,  4, 32, 32, 54);

    splat_kernel<<<(BATCH * NPART) / 256, 256, 0, stream>>>(locs, data, density, g4);
    convert_kernel<<<NVOX / 256, 256, 0, stream>>>((const float4*)g4, (short8*)g8);

    const int CGRID = BATCH * 64 * 32;   // 4096 workgroups
    mfma_conv_kernel< 1, 14, false><<<CGRID, 256, 0, stream>>>(g8, Bp0, b0, a0, gA);
    mfma_conv_kernel< 4, 54, false><<<CGRID, 256, 0, stream>>>(gA, Bp1, b1, a1, gB);
    mfma_conv_kernel< 4, 54, false><<<CGRID, 256, 0, stream>>>(gB, Bp2, b2, a2, gA);
    mfma_conv_kernel< 4, 54, true ><<<CGRID, 256, 0, stream>>>(gA, Bp3, b3, b3, gF);

    gather_kernel<<<(BATCH * NPART) / 256, 256, 0, stream>>>(gF, locs, out);
}

// Round 4
// 345.515 us; speedup vs baseline: 2.0435x; 2.0435x over previous
//
#include <hip/hip_runtime.h>

#define BATCH 2
#define NPART 32768
#define GD 64
#define NVOX (BATCH * GD * GD * GD)   // 524288

typedef unsigned short ushortT;
typedef __attribute__((ext_vector_type(8))) short short8;
typedef __attribute__((ext_vector_type(16))) float float16;

__device__ __forceinline__ float poly6_c() {
    const double H9 = 1.0 / 35184372088832.0; // 0.03125^9 == 2^-45 (exact)
    return (float)(315.0 / (64.0 * 3.14159265358979323846 * H9));
}

__device__ __forceinline__ ushortT bf16_rne(float f) {
    unsigned int u = __float_as_uint(f);
    u = (u + 0x7fffu + ((u >> 16) & 1u)) >> 16;   // round-to-nearest-even
    return (ushortT)u;
}

__device__ __forceinline__ int imax(int a, int b) { return a > b ? a : b; }
__device__ __forceinline__ int imin(int a, int b) { return a < b ? a : b; }

// ---------------- zero ints (bin counts + cursors) ----------------
__global__ void zero_ints_kernel(int* __restrict__ p, int n) {
    int t = blockIdx.x * blockDim.x + threadIdx.x;
    if (t < n) p[t] = 0;
}

// ---------------- bin count: particle -> 4^3-cell bin histogram ----------------
__global__ __launch_bounds__(256) void bin_count_kernel(
    const float* __restrict__ locs, int* __restrict__ counts) {
    int t = blockIdx.x * blockDim.x + threadIdx.x;
    if (t >= BATCH * NPART) return;
    int b = t >> 15;
    int bx = (int)floorf(locs[t * 3 + 0] * 64.0f);
    int by = (int)floorf(locs[t * 3 + 1] * 64.0f);
    int bz = (int)floorf(locs[t * 3 + 2] * 64.0f);
    int bin = (((bx >> 2) * 16) + (by >> 2)) * 16 + (bz >> 2);
    atomicAdd(&counts[b * 4096 + bin], 1);
}

// ---------------- exclusive scan of 8192 bin counts (single WG) ----------------
__global__ __launch_bounds__(256) void scan_kernel(
    const int* __restrict__ counts, int* __restrict__ offsets) {
    __shared__ int partials[256];
    int tid = threadIdx.x;
    int base = tid * 32;
    int local[32];
    int s = 0;
#pragma unroll
    for (int k = 0; k < 32; ++k) { local[k] = counts[base + k]; s += local[k]; }
    partials[tid] = s;
    __syncthreads();
    for (int off = 1; off < 256; off <<= 1) {
        int v = 0;
        if (tid >= off) v = partials[tid - off];
        __syncthreads();
        if (tid >= off) partials[tid] += v;
        __syncthreads();
    }
    int run = partials[tid] - s;       // exclusive prefix of this chunk
#pragma unroll
    for (int k = 0; k < 32; ++k) { offsets[base + k] = run; run += local[k]; }
    if (tid == 255) offsets[8192] = partials[255];
}

// ---------------- scatter particles into binned payload ----------------
// payload[idx]: {px,py,pz,v0, v1,v2,v3,0}
__global__ __launch_bounds__(256) void bin_scatter_kernel(
    const float* __restrict__ locs, const float* __restrict__ data,
    const float* __restrict__ density, const int* __restrict__ offsets,
    int* __restrict__ cursor, float* __restrict__ payload) {
    int t = blockIdx.x * blockDim.x + threadIdx.x;
    if (t >= BATCH * NPART) return;
    int b = t >> 15;
    float px = locs[t * 3 + 0];
    float py = locs[t * 3 + 1];
    float pz = locs[t * 3 + 2];
    int bx = (int)floorf(px * 64.0f);
    int by = (int)floorf(py * 64.0f);
    int bz = (int)floorf(pz * 64.0f);
    int bb = b * 4096 + ((((bx >> 2) * 16) + (by >> 2)) * 16 + (bz >> 2));
    int slot = atomicAdd(&cursor[bb], 1);
    int idx = offsets[bb] + slot;
    float inv_d = 1.0f / density[t];
    float4 p0 = {px, py, pz, data[t * 4 + 0] * inv_d};
    float4 p1 = {data[t * 4 + 1] * inv_d, data[t * 4 + 2] * inv_d,
                 data[t * 4 + 3] * inv_d, 0.f};
    *(float4*)(payload + idx * 8)     = p0;
    *(float4*)(payload + idx * 8 + 4) = p1;
}

// ---------------- gather-splat: one WG owns an 8^3 region, LDS accumulate ----
// writes bf16 8-ch grid directly (ch 4..7 = 0); full coverage, no global atomics.
__global__ __launch_bounds__(256) void splat_gather_kernel(
    const float* __restrict__ payload, const int* __restrict__ offsets,
    ushortT* __restrict__ g8) {
    __shared__ float acc[8 * 8 * 8 * 4];          // [x][y][z][c]
    __shared__ int segS[16];
    __shared__ int segP[17];
    __shared__ int nsTot[2];

    int wg = blockIdx.x;                          // 1024 = b*512 + sb
    int sb = wg & 511, b = wg >> 9;
    int X0 = (sb >> 6) * 8, Y0 = ((sb >> 3) & 7) * 8, Z0 = (sb & 7) * 8;
    int tid = threadIdx.x;

    for (int i = tid; i < 2048; i += 256) acc[i] = 0.f;

    if (tid == 0) {
        int bxlo = imax(0, (X0 - 2) >> 2), bxhi = imin(15, (X0 + 9) >> 2);
        int bylo = imax(0, (Y0 - 2) >> 2), byhi = imin(15, (Y0 + 9) >> 2);
        int bzlo = imax(0, (Z0 - 2) >> 2), bzhi = imin(15, (Z0 + 9) >> 2);
        int ns = 0, p = 0;
        for (int bx = bxlo; bx <= bxhi; ++bx)
            for (int by = bylo; by <= byhi; ++by) {
                int row = b * 4096 + (bx * 16 + by) * 16;
                int s = offsets[row + bzlo];
                int e = offsets[row + bzhi + 1];   // contiguous in bz
                segS[ns] = s;
                segP[ns] = p;
                p += e - s;
                ++ns;
            }
        segP[ns] = p;
        nsTot[0] = ns;
        nsTot[1] = p;
    }
    __syncthreads();

    const float step = 0.015625f;
    const float h2 = 0.03125f * 0.03125f;
    const float cc = poly6_c();
    int total = nsTot[1];

    for (int j = tid; j < total; j += 256) {
        int k = 0;
        while (j >= segP[k + 1]) ++k;
        int idx = segS[k] + (j - segP[k]);
        const float4 p0 = *(const float4*)(payload + idx * 8);
        const float4 p1 = *(const float4*)(payload + idx * 8 + 4);
        float px = p0.x, py = p0.y, pz = p0.z;
        float v0 = p0.w, v1 = p1.x, v2 = p1.y, v3 = p1.z;

        int bx = (int)floorf(px * 64.0f);
        int by = (int)floorf(py * 64.0f);
        int bz = (int)floorf(pz * 64.0f);
        int xlo = imax(bx - 2, X0), xhi = imin(bx + 2, X0 + 7);
        int ylo = imax(by - 2, Y0), yhi = imin(by + 2, Y0 + 7);
        int zlo = imax(bz - 2, Z0), zhi = imin(bz + 2, Z0 + 7);
        if (xlo > xhi || ylo > yhi || zlo > zhi) continue;

        for (int x = xlo; x <= xhi; ++x) {
            float cx = ((float)x + 0.5f) * step - px;
            float dx2 = cx * cx;
            for (int y = ylo; y <= yhi; ++y) {
                float cy = ((float)y + 0.5f) * step - py;
                float dxy2 = dx2 + cy * cy;
                if (dxy2 > h2) continue;
                for (int z = zlo; z <= zhi; ++z) {
                    float cz = ((float)z + 0.5f) * step - pz;
                    float d2 = dxy2 + cz * cz;
                    if (d2 > h2) continue;
                    float u = h2 - d2;
                    float w = cc * u * u * u;
                    float* ap = &acc[((((x - X0) * 8) + (y - Y0)) * 8 + (z - Z0)) * 4];
                    atomicAdd(ap + 0, w * v0);     // ds_add_f32 (LDS-native)
                    atomicAdd(ap + 1, w * v1);
                    atomicAdd(ap + 2, w * v2);
                    atomicAdd(ap + 3, w * v3);
                }
            }
        }
    }
    __syncthreads();

    for (int i = tid; i < 512; i += 256) {        // interior cell i
        int x = i >> 6, y = (i >> 3) & 7, z = i & 7;
        size_t cell = (size_t)(((b * 64 + X0 + x) * 64 + (Y0 + y)) * 64 + (Z0 + z));
        short8 o;
        o[0] = (short)bf16_rne(acc[i * 4 + 0]);
        o[1] = (short)bf16_rne(acc[i * 4 + 1]);
        o[2] = (short)bf16_rne(acc[i * 4 + 2]);
        o[3] = (short)bf16_rne(acc[i * 4 + 3]);
        o[4] = 0; o[5] = 0; o[6] = 0; o[7] = 0;
        *(short8*)(g8 + cell * 8) = o;
    }
}

// ---------------- weight repack into MFMA B-fragment order ----------------
__global__ void repack_kernel(const float* __restrict__ W, short* __restrict__ Bp,
                              int O, int I, int CINP, int KT) {
    int t = blockIdx.x * blockDim.x + threadIdx.x;
    int total = KT * 512;
    if (t >= total) return;
    int kt = t >> 9;
    int l  = (t >> 3) & 63;
    int j  = t & 7;
    int n = l & 31, q = l >> 5;
    int k = kt * 16 + 8 * q + j;
    int tap = k / CINP;
    int ic  = k - tap * CINP;
    float v = 0.f;
    if (tap < 27 && ic < I && n < O) v = W[(n * I + ic) * 27 + tap];
    Bp[t] = (short)bf16_rne(v);
}

// ---------------- MFMA implicit-GEMM 3x3x3 conv ----------------
template <int ICG, int KT, bool FINAL>
__global__ __launch_bounds__(256) void mfma_conv_kernel(
    const ushortT* __restrict__ in, const short* __restrict__ Bpack,
    const float* __restrict__ bias, const float* __restrict__ alpha,
    void* __restrict__ outv) {
    constexpr int CIN = ICG * 8;
    __shared__ short lds[12 * ICG * 66 * 8];       // [col12][icg][z66][8ch]
    int wg = blockIdx.x;                           // 2*64*32 = 4096
    int yp = wg & 31, x = (wg >> 5) & 63, b = wg >> 11;
    int y0 = yp * 2;
    int tid = threadIdx.x;

    const int NCH = 12 * ICG * 66;                 // 16B chunks
    for (int cc = tid; cc < NCH; cc += 256) {
        int col = cc / (ICG * 66);
        int rem = cc - col * (ICG * 66);
        int icg = rem / 66;
        int z66 = rem - icg * 66;
        int gx = x + (col >> 2) - 1;               // col = dx*4 + ty
        int gy = y0 + (col & 3) - 1;
        int z  = z66 - 1;
        short8 v = short8{0,0,0,0,0,0,0,0};
        if ((unsigned)gx < 64u && (unsigned)gy < 64u && (unsigned)z < 64u)
            v = *(const short8*)(in + ((size_t)(((b * 64 + gx) * 64 + gy) * 64 + z)) * CIN + icg * 8);
        *(short8*)(lds + cc * 8) = v;
    }
    __syncthreads();

    int l = tid & 63, w = tid >> 6;
    int ycol = w >> 1, mz = (w & 1) * 32;
    int n = l & 31, q = l >> 5;

    float bval = FINAL ? (n < 4 ? bias[n] : 0.f) : bias[n];
    float16 acc;
#pragma unroll
    for (int r = 0; r < 16; ++r) acc[r] = bval;

    const short* bp = Bpack + (size_t)l * 8;
    int laneBase = (mz + (l & 31)) * 8;
    int ycolOfs  = ycol * (ICG * 66) * 8;

#pragma unroll
    for (int kt = 0; kt < KT; ++kt) {
        short8 bfrag = *(const short8*)(bp + kt * 512);
        int aofs;
        if constexpr (ICG == 1) {
            int tap0 = kt * 2, tap1 = kt * 2 + 1;
            if (tap1 > 26) tap1 = 26;              // B is zero there; any valid addr
            int dx0 = tap0 / 9, r0 = tap0 - dx0 * 9, dy0 = r0 / 3, dz0 = r0 - dy0 * 3;
            int dx1 = tap1 / 9, r1 = tap1 - dx1 * 9, dy1 = r1 / 3, dz1 = r1 - dy1 * 3;
            int c0 = ((dx0 * 4 + dy0) * 66 + dz0) * 8;
            int c1 = ((dx1 * 4 + dy1) * 66 + dz1) * 8;
            aofs = q ? c1 : c0;
        } else {
            int tap = kt >> 1;
            int dx = tap / 9, rr = tap - dx * 9, dy = rr / 3, dz = rr - dy * 3;
            int icg = (kt & 1) * 2 + q;
            aofs = (((dx * 4 + dy) * ICG + icg) * 66 + dz) * 8;
        }
        short8 afrag = *(const short8*)(lds + aofs + ycolOfs + laneBase);
        acc = __builtin_amdgcn_mfma_f32_32x32x16_bf16(afrag, bfrag, acc, 0, 0, 0);
    }

    int ygl = y0 + ycol;
    size_t base = (size_t)(((b * 64 + x) * 64 + ygl) * 64);
    if (FINAL) {
        float* out = (float*)outv;
        if (n < 4) {
#pragma unroll
            for (int r = 0; r < 16; ++r) {
                int z = mz + (r & 3) + 8 * (r >> 2) + 4 * q;
                out[(base + z) * 4 + n] = acc[r];
            }
        }
    } else {
        float a = alpha[0];
        ushortT* out = (ushortT*)outv;
#pragma unroll
        for (int r = 0; r < 16; ++r) {
            int z = mz + (r & 3) + 8 * (r >> 2) + 4 * q;
            float v = acc[r];
            v = v >= 0.f ? v : a * v;
            out[(base + z) * 32 + n] = bf16_rne(v);
        }
    }
}

// ---------------- grid2particles (trilinear gather, fp32 grid) ----------------
__global__ __launch_bounds__(256) void gather_kernel(
    const float* __restrict__ grid, const float* __restrict__ locs,
    float* __restrict__ out) {
    int t = blockIdx.x * blockDim.x + threadIdx.x;
    if (t >= BATCH * NPART) return;
    int b = t >> 15;

    float px = locs[t * 3 + 0] * 64.0f - 0.5f;
    float py = locs[t * 3 + 1] * 64.0f - 0.5f;
    float pz = locs[t * 3 + 2] * 64.0f - 0.5f;
    int ix = (int)floorf(px);
    int iy = (int)floorf(py);
    int iz = (int)floorf(pz);
    float fx = px - (float)ix;
    float fy = py - (float)iy;
    float fz = pz - (float)iz;

    const float* gb = grid + (size_t)b * GD * GD * GD * 4;
    float o0 = 0.f, o1 = 0.f, o2 = 0.f, o3 = 0.f;

#pragma unroll
    for (int dx = 0; dx < 2; ++dx) {
        int x = ix + dx;
        if ((unsigned)x > 63u) continue;
        float wx = dx ? fx : 1.0f - fx;
#pragma unroll
        for (int dy = 0; dy < 2; ++dy) {
            int y = iy + dy;
            if ((unsigned)y > 63u) continue;
            float wy = dy ? fy : 1.0f - fy;
#pragma unroll
            for (int dz = 0; dz < 2; ++dz) {
                int z = iz + dz;
                if ((unsigned)z > 63u) continue;
                float wz = dz ? fz : 1.0f - fz;
                float w = wx * wy * wz;
                const float4 g = *(const float4*)(gb + (size_t)(((x * GD) + y) * GD + z) * 4);
                o0 += w * g.x; o1 += w * g.y; o2 += w * g.z; o3 += w * g.w;
            }
        }
    }
    out[t * 4 + 0] = o0;
    out[t * 4 + 1] = o1;
    out[t * 4 + 2] = o2;
    out[t * 4 + 3] = o3;
}

extern "C" void kernel_launch(void* const* d_in, const int* in_sizes, int n_in,
                              void* d_out, int out_size, void* d_ws, size_t ws_size,
                              hipStream_t stream) {
    const float* locs    = (const float*)d_in[0];
    const float* data    = (const float*)d_in[1];
    const float* density = (const float*)d_in[2];
    const float* W0 = (const float*)d_in[3];
    const float* b0 = (const float*)d_in[4];
    const float* W1 = (const float*)d_in[5];
    const float* b1 = (const float*)d_in[6];
    const float* W2 = (const float*)d_in[7];
    const float* b2 = (const float*)d_in[8];
    const float* W3 = (const float*)d_in[9];
    const float* b3 = (const float*)d_in[10];
    const float* a0 = (const float*)d_in[11];
    const float* a1 = (const float*)d_in[12];
    const float* a2 = (const float*)d_in[13];
    float* out = (float*)d_out;

    char* ws = (char*)d_ws;
    ushortT* g8  = (ushortT*)(ws);                       // 8 MB bf16 8ch
    ushortT* gA  = (ushortT*)(ws + 8388608);             // 33.5 MB bf16 32ch
    ushortT* gB  = (ushortT*)(ws + 41943040);            // 33.5 MB bf16 32ch
    float*  gF   = (float*)(ws + 75497472);              // 8 MB fp32 4ch
    short*  Bp0  = (short*)(ws + 83886080);
    short*  Bp1  = (short*)(ws + 83900416);
    short*  Bp2  = (short*)(ws + 83955712);
    short*  Bp3  = (short*)(ws + 84011008);
    int*   counts  = (int*)(ws + 84066304);              // 8192 ints
    int*   cursor  = (int*)(ws + 84099072);              // 8192 ints
    int*   offsets = (int*)(ws + 84131840);              // 8193 ints
    float* payload = (float*)(ws + 84164624);            // 65536*8 floats = 2 MB

    // ---- binning (counts+cursor zeroed each call; ws is poisoned 0xAA) ----
    zero_ints_kernel<<<(16384 + 255) / 256, 256, 0, stream>>>(counts, 16384); // counts+cursor contiguous
    bin_count_kernel<<<(BATCH * NPART) / 256, 256, 0, stream>>>(locs, counts);
    scan_kernel<<<1, 256, 0, stream>>>(counts, offsets);
    bin_scatter_kernel<<<(BATCH * NPART) / 256, 256, 0, stream>>>(
        locs, data, density, offsets, cursor, payload);

    // ---- weight repack ----
    repack_kernel<<<(14 * 512 + 255) / 256, 256, 0, stream>>>(W0, Bp0, 32,  4,  8, 14);
    repack_kernel<<<(54 * 512 + 255) / 256, 256, 0, stream>>>(W1, Bp1, 32, 32, 32, 54);
    repack_kernel<<<(54 * 512 + 255) / 256, 256, 0, stream>>>(W2, Bp2, 32, 32, 32, 54);
    repack_kernel<<<(54 * 512 + 255) / 256, 256, 0, stream>>>(W3, Bp3,  4, 32, 32, 54);

    // ---- particles -> bf16 grid (LDS-aggregated, owner-writes) ----
    splat_gather_kernel<<<BATCH * 512, 256, 0, stream>>>(payload, offsets, g8);

    // ---- conv chain ----
    const int CGRID = BATCH * 64 * 32;   // 4096 workgroups
    mfma_conv_kernel< 1, 14, false><<<CGRID, 256, 0, stream>>>(g8, Bp0, b0, a0, gA);
    mfma_conv_kernel< 4, 54, false><<<CGRID, 256, 0, stream>>>(gA, Bp1, b1, a1, gB);
    mfma_conv_kernel< 4, 54, false><<<CGRID, 256, 0, stream>>>(gB, Bp2, b2, a2, gA);
    mfma_conv_kernel< 4, 54, true ><<<CGRID, 256, 0, stream>>>(gA, Bp3, b3, b3, gF);

    // ---- grid -> particles ----
    gather_kernel<<<(BATCH * NPART) / 256, 256, 0, stream>>>(gF, locs, out);
}

// Round 5
// 339.199 us; speedup vs baseline: 2.0815x; 1.0186x over previous
//
#include <hip/hip_runtime.h>

#define BATCH 2
#define NPART 32768
#define GD 64
#define NVOX (BATCH * GD * GD * GD)   // 524288

typedef unsigned short ushortT;
typedef __attribute__((ext_vector_type(8))) short short8;
typedef __attribute__((ext_vector_type(16))) float float16;

__device__ __forceinline__ float poly6_c() {
    const double H9 = 1.0 / 35184372088832.0; // 0.03125^9 == 2^-45 (exact)
    return (float)(315.0 / (64.0 * 3.14159265358979323846 * H9));
}

__device__ __forceinline__ ushortT bf16_rne(float f) {
    unsigned int u = __float_as_uint(f);
    u = (u + 0x7fffu + ((u >> 16) & 1u)) >> 16;   // round-to-nearest-even
    return (ushortT)u;
}

__device__ __forceinline__ int imax(int a, int b) { return a > b ? a : b; }
__device__ __forceinline__ int imin(int a, int b) { return a < b ? a : b; }

// ---------------- zero ints (bin counts + cursors) ----------------
__global__ void zero_ints_kernel(int* __restrict__ p, int n) {
    int t = blockIdx.x * blockDim.x + threadIdx.x;
    if (t < n) p[t] = 0;
}

// ---------------- bin count: particle -> 4^3-cell bin histogram ----------------
__global__ __launch_bounds__(256) void bin_count_kernel(
    const float* __restrict__ locs, int* __restrict__ counts) {
    int t = blockIdx.x * blockDim.x + threadIdx.x;
    if (t >= BATCH * NPART) return;
    int b = t >> 15;
    int bx = (int)floorf(locs[t * 3 + 0] * 64.0f);
    int by = (int)floorf(locs[t * 3 + 1] * 64.0f);
    int bz = (int)floorf(locs[t * 3 + 2] * 64.0f);
    int bin = (((bx >> 2) * 16) + (by >> 2)) * 16 + (bz >> 2);
    atomicAdd(&counts[b * 4096 + bin], 1);
}

// ---------------- exclusive scan of 8192 bin counts (single WG) ----------------
__global__ __launch_bounds__(256) void scan_kernel(
    const int* __restrict__ counts, int* __restrict__ offsets) {
    __shared__ int partials[256];
    int tid = threadIdx.x;
    int base = tid * 32;
    int local[32];
    int s = 0;
#pragma unroll
    for (int k = 0; k < 32; ++k) { local[k] = counts[base + k]; s += local[k]; }
    partials[tid] = s;
    __syncthreads();
    for (int off = 1; off < 256; off <<= 1) {
        int v = 0;
        if (tid >= off) v = partials[tid - off];
        __syncthreads();
        if (tid >= off) partials[tid] += v;
        __syncthreads();
    }
    int run = partials[tid] - s;       // exclusive prefix of this chunk
#pragma unroll
    for (int k = 0; k < 32; ++k) { offsets[base + k] = run; run += local[k]; }
    if (tid == 255) offsets[8192] = partials[255];
}

// ---------------- scatter particles into binned payload ----------------
// payload[idx]: {px,py,pz,v0, v1,v2,v3,0}
__global__ __launch_bounds__(256) void bin_scatter_kernel(
    const float* __restrict__ locs, const float* __restrict__ data,
    const float* __restrict__ density, const int* __restrict__ offsets,
    int* __restrict__ cursor, float* __restrict__ payload) {
    int t = blockIdx.x * blockDim.x + threadIdx.x;
    if (t >= BATCH * NPART) return;
    int b = t >> 15;
    float px = locs[t * 3 + 0];
    float py = locs[t * 3 + 1];
    float pz = locs[t * 3 + 2];
    int bx = (int)floorf(px * 64.0f);
    int by = (int)floorf(py * 64.0f);
    int bz = (int)floorf(pz * 64.0f);
    int bb = b * 4096 + ((((bx >> 2) * 16) + (by >> 2)) * 16 + (bz >> 2));
    int slot = atomicAdd(&cursor[bb], 1);
    int idx = offsets[bb] + slot;
    float inv_d = 1.0f / density[t];
    float4 p0 = {px, py, pz, data[t * 4 + 0] * inv_d};
    float4 p1 = {data[t * 4 + 1] * inv_d, data[t * 4 + 2] * inv_d,
                 data[t * 4 + 3] * inv_d, 0.f};
    *(float4*)(payload + idx * 8)     = p0;
    *(float4*)(payload + idx * 8 + 4) = p1;
}

// ---------------- cell-owner gather splat: no atomics at all ----------------
// WG owns an 8^3 region; thread owns 2 cells (same x,y; z and z+4);
// halo particles staged into LDS in 256-chunks; register accumulation.
__global__ __launch_bounds__(256) void splat_gather_kernel(
    const float* __restrict__ payload, const int* __restrict__ offsets,
    ushortT* __restrict__ g8) {
    __shared__ float plist[256 * 8];              // particle chunk
    __shared__ int segS[16];
    __shared__ int segP[17];
    __shared__ int nsTot[2];

    int wg = blockIdx.x;                          // 1024 = b*512 + sb
    int sb = wg & 511, b = wg >> 9;
    int X0 = (sb >> 6) * 8, Y0 = ((sb >> 3) & 7) * 8, Z0 = (sb & 7) * 8;
    int tid = threadIdx.x;

    if (tid == 0) {
        int bxlo = imax(0, (X0 - 2) >> 2), bxhi = imin(15, (X0 + 9) >> 2);
        int bylo = imax(0, (Y0 - 2) >> 2), byhi = imin(15, (Y0 + 9) >> 2);
        int bzlo = imax(0, (Z0 - 2) >> 2), bzhi = imin(15, (Z0 + 9) >> 2);
        int ns = 0, p = 0;
        for (int bx = bxlo; bx <= bxhi; ++bx)
            for (int by = bylo; by <= byhi; ++by) {
                int row = b * 4096 + (bx * 16 + by) * 16;
                int s = offsets[row + bzlo];
                int e = offsets[row + bzhi + 1];   // contiguous in bz
                segS[ns] = s;
                segP[ns] = p;
                p += e - s;
                ++ns;
            }
        segP[ns] = p;
        nsTot[0] = ns;
        nsTot[1] = p;
    }
    __syncthreads();

    const float step = 0.015625f;
    const float h2 = 0.03125f * 0.03125f;
    const float cc = poly6_c();
    int total = nsTot[1];

    // this thread's two cells: wave w covers x-block (w>>1), y-block (w&1), all z
    int l = tid & 63, w = tid >> 6;
    int cx = X0 + 4 * (w >> 1) + (l >> 4);
    int cy = Y0 + 4 * (w & 1) + ((l >> 2) & 3);
    int cz0 = Z0 + (l & 3);
    float xc  = ((float)cx  + 0.5f) * step;
    float yc  = ((float)cy  + 0.5f) * step;
    float zc0 = ((float)cz0 + 0.5f) * step;
    float zc1 = zc0 + 4.0f * step;

    float a00 = 0.f, a01 = 0.f, a02 = 0.f, a03 = 0.f;   // cell (cz0)
    float a10 = 0.f, a11 = 0.f, a12 = 0.f, a13 = 0.f;   // cell (cz0+4)

    int nchunks = (total + 255) >> 8;
    for (int ch = 0; ch < nchunks; ++ch) {
        __syncthreads();
        int jj = (ch << 8) + tid;
        if (jj < total) {
            int k = 0;
            while (jj >= segP[k + 1]) ++k;
            int idx = segS[k] + (jj - segP[k]);
            *(float4*)(plist + tid * 8)     = *(const float4*)(payload + idx * 8);
            *(float4*)(plist + tid * 8 + 4) = *(const float4*)(payload + idx * 8 + 4);
        }
        __syncthreads();
        int cnt = imin(256, total - (ch << 8));
        for (int p = 0; p < cnt; ++p) {
            float4 pa = *(const float4*)(plist + p * 8);     // broadcast read
            float dx = pa.x - xc, dy = pa.y - yc;
            float dxy2 = fmaf(dy, dy, dx * dx);
            if (!__any(dxy2 <= h2)) continue;                // wave-coherent skip
            float4 pv = *(const float4*)(plist + p * 8 + 4);
            float dz0 = pa.z - zc0;
            float d20 = fmaf(dz0, dz0, dxy2);
            float u0 = fmaxf(h2 - d20, 0.f);
            float w0 = (cc * u0) * (u0 * u0);
            a00 = fmaf(w0, pa.w, a00);
            a01 = fmaf(w0, pv.x, a01);
            a02 = fmaf(w0, pv.y, a02);
            a03 = fmaf(w0, pv.z, a03);
            float dz1 = pa.z - zc1;
            float d21 = fmaf(dz1, dz1, dxy2);
            float u1 = fmaxf(h2 - d21, 0.f);
            float w1 = (cc * u1) * (u1 * u1);
            a10 = fmaf(w1, pa.w, a10);
            a11 = fmaf(w1, pv.x, a11);
            a12 = fmaf(w1, pv.y, a12);
            a13 = fmaf(w1, pv.z, a13);
        }
    }

    // write both cells as bf16 8-ch (ch 4..7 = 0)
    size_t cellBase = (size_t)(((b * 64 + cx) * 64 + cy) * 64);
    short8 o;
    o[0] = (short)bf16_rne(a00); o[1] = (short)bf16_rne(a01);
    o[2] = (short)bf16_rne(a02); o[3] = (short)bf16_rne(a03);
    o[4] = 0; o[5] = 0; o[6] = 0; o[7] = 0;
    *(short8*)(g8 + (cellBase + cz0) * 8) = o;
    o[0] = (short)bf16_rne(a10); o[1] = (short)bf16_rne(a11);
    o[2] = (short)bf16_rne(a12); o[3] = (short)bf16_rne(a13);
    *(short8*)(g8 + (cellBase + cz0 + 4) * 8) = o;
}

// ---------------- weight repack into MFMA B-fragment order ----------------
__global__ void repack_kernel(const float* __restrict__ W, short* __restrict__ Bp,
                              int O, int I, int CINP, int KT) {
    int t = blockIdx.x * blockDim.x + threadIdx.x;
    int total = KT * 512;
    if (t >= total) return;
    int kt = t >> 9;
    int l  = (t >> 3) & 63;
    int j  = t & 7;
    int n = l & 31, q = l >> 5;
    int k = kt * 16 + 8 * q + j;
    int tap = k / CINP;
    int ic  = k - tap * CINP;
    float v = 0.f;
    if (tap < 27 && ic < I && n < O) v = W[(n * I + ic) * 27 + tap];
    Bp[t] = (short)bf16_rne(v);
}

// ---------------- MFMA implicit-GEMM 3x3x3 conv ----------------
template <int ICG, int KT, bool FINAL>
__global__ __launch_bounds__(256) void mfma_conv_kernel(
    const ushortT* __restrict__ in, const short* __restrict__ Bpack,
    const float* __restrict__ bias, const float* __restrict__ alpha,
    void* __restrict__ outv) {
    constexpr int CIN = ICG * 8;
    __shared__ short lds[12 * ICG * 66 * 8];       // [col12][icg][z66][8ch]
    int wg = blockIdx.x;                           // 2*64*32 = 4096
    int yp = wg & 31, x = (wg >> 5) & 63, b = wg >> 11;
    int y0 = yp * 2;
    int tid = threadIdx.x;

    const int NCH = 12 * ICG * 66;                 // 16B chunks
    for (int cc = tid; cc < NCH; cc += 256) {
        int col = cc / (ICG * 66);
        int rem = cc - col * (ICG * 66);
        int icg = rem / 66;
        int z66 = rem - icg * 66;
        int gx = x + (col >> 2) - 1;               // col = dx*4 + ty
        int gy = y0 + (col & 3) - 1;
        int z  = z66 - 1;
        short8 v = short8{0,0,0,0,0,0,0,0};
        if ((unsigned)gx < 64u && (unsigned)gy < 64u && (unsigned)z < 64u)
            v = *(const short8*)(in + ((size_t)(((b * 64 + gx) * 64 + gy) * 64 + z)) * CIN + icg * 8);
        *(short8*)(lds + cc * 8) = v;
    }
    __syncthreads();

    int l = tid & 63, w = tid >> 6;
    int ycol = w >> 1, mz = (w & 1) * 32;
    int n = l & 31, q = l >> 5;

    float bval = FINAL ? (n < 4 ? bias[n] : 0.f) : bias[n];
    float16 acc;
#pragma unroll
    for (int r = 0; r < 16; ++r) acc[r] = bval;

    const short* bp = Bpack + (size_t)l * 8;
    int laneBase = (mz + (l & 31)) * 8;
    int ycolOfs  = ycol * (ICG * 66) * 8;

#pragma unroll
    for (int kt = 0; kt < KT; ++kt) {
        short8 bfrag = *(const short8*)(bp + kt * 512);
        int aofs;
        if constexpr (ICG == 1) {
            int tap0 = kt * 2, tap1 = kt * 2 + 1;
            if (tap1 > 26) tap1 = 26;              // B is zero there; any valid addr
            int dx0 = tap0 / 9, r0 = tap0 - dx0 * 9, dy0 = r0 / 3, dz0 = r0 - dy0 * 3;
            int dx1 = tap1 / 9, r1 = tap1 - dx1 * 9, dy1 = r1 / 3, dz1 = r1 - dy1 * 3;
            int c0 = ((dx0 * 4 + dy0) * 66 + dz0) * 8;
            int c1 = ((dx1 * 4 + dy1) * 66 + dz1) * 8;
            aofs = q ? c1 : c0;
        } else {
            int tap = kt >> 1;
            int dx = tap / 9, rr = tap - dx * 9, dy = rr / 3, dz = rr - dy * 3;
            int icg = (kt & 1) * 2 + q;
            aofs = (((dx * 4 + dy) * ICG + icg) * 66 + dz) * 8;
        }
        short8 afrag = *(const short8*)(lds + aofs + ycolOfs + laneBase);
        acc = __builtin_amdgcn_mfma_f32_32x32x16_bf16(afrag, bfrag, acc, 0, 0, 0);
    }

    int ygl = y0 + ycol;
    size_t base = (size_t)(((b * 64 + x) * 64 + ygl) * 64);
    if (FINAL) {
        float* out = (float*)outv;
        if (n < 4) {
#pragma unroll
            for (int r = 0; r < 16; ++r) {
                int z = mz + (r & 3) + 8 * (r >> 2) + 4 * q;
                out[(base + z) * 4 + n] = acc[r];
            }
        }
    } else {
        float a = alpha[0];
        ushortT* out = (ushortT*)outv;
#pragma unroll
        for (int r = 0; r < 16; ++r) {
            int z = mz + (r & 3) + 8 * (r >> 2) + 4 * q;
            float v = acc[r];
            v = v >= 0.f ? v : a * v;
            out[(base + z) * 32 + n] = bf16_rne(v);
        }
    }
}

// ---------------- grid2particles (trilinear gather, fp32 grid) ----------------
__global__ __launch_bounds__(256) void gather_kernel(
    const float* __restrict__ grid, const float* __restrict__ locs,
    float* __restrict__ out) {
    int t = blockIdx.x * blockDim.x + threadIdx.x;
    if (t >= BATCH * NPART) return;
    int b = t >> 15;

    float px = locs[t * 3 + 0] * 64.0f - 0.5f;
    float py = locs[t * 3 + 1] * 64.0f - 0.5f;
    float pz = locs[t * 3 + 2] * 64.0f - 0.5f;
    int ix = (int)floorf(px);
    int iy = (int)floorf(py);
    int iz = (int)floorf(pz);
    float fx = px - (float)ix;
    float fy = py - (float)iy;
    float fz = pz - (float)iz;

    const float* gb = grid + (size_t)b * GD * GD * GD * 4;
    float o0 = 0.f, o1 = 0.f, o2 = 0.f, o3 = 0.f;

#pragma unroll
    for (int dx = 0; dx < 2; ++dx) {
        int x = ix + dx;
        if ((unsigned)x > 63u) continue;
        float wx = dx ? fx : 1.0f - fx;
#pragma unroll
        for (int dy = 0; dy < 2; ++dy) {
            int y = iy + dy;
            if ((unsigned)y > 63u) continue;
            float wy = dy ? fy : 1.0f - fy;
#pragma unroll
            for (int dz = 0; dz < 2; ++dz) {
                int z = iz + dz;
                if ((unsigned)z > 63u) continue;
                float wz = dz ? fz : 1.0f - fz;
                float w = wx * wy * wz;
                const float4 g = *(const float4*)(gb + (size_t)(((x * GD) + y) * GD + z) * 4);
                o0 += w * g.x; o1 += w * g.y; o2 += w * g.z; o3 += w * g.w;
            }
        }
    }
    out[t * 4 + 0] = o0;
    out[t * 4 + 1] = o1;
    out[t * 4 + 2] = o2;
    out[t * 4 + 3] = o3;
}

extern "C" void kernel_launch(void* const* d_in, const int* in_sizes, int n_in,
                              void* d_out, int out_size, void* d_ws, size_t ws_size,
                              hipStream_t stream) {
    const float* locs    = (const float*)d_in[0];
    const float* data    = (const float*)d_in[1];
    const float* density = (const float*)d_in[2];
    const float* W0 = (const float*)d_in[3];
    const float* b0 = (const float*)d_in[4];
    const float* W1 = (const float*)d_in[5];
    const float* b1 = (const float*)d_in[6];
    const float* W2 = (const float*)d_in[7];
    const float* b2 = (const float*)d_in[8];
    const float* W3 = (const float*)d_in[9];
    const float* b3 = (const float*)d_in[10];
    const float* a0 = (const float*)d_in[11];
    const float* a1 = (const float*)d_in[12];
    const float* a2 = (const float*)d_in[13];
    float* out = (float*)d_out;

    char* ws = (char*)d_ws;
    ushortT* g8  = (ushortT*)(ws);                       // 8 MB bf16 8ch
    ushortT* gA  = (ushortT*)(ws + 8388608);             // 33.5 MB bf16 32ch
    ushortT* gB  = (ushortT*)(ws + 41943040);            // 33.5 MB bf16 32ch
    float*  gF   = (float*)(ws + 75497472);              // 8 MB fp32 4ch
    short*  Bp0  = (short*)(ws + 83886080);
    short*  Bp1  = (short*)(ws + 83900416);
    short*  Bp2  = (short*)(ws + 83955712);
    short*  Bp3  = (short*)(ws + 84011008);
    int*   counts  = (int*)(ws + 84066304);              // 8192 ints
    int*   cursor  = (int*)(ws + 84099072);              // 8192 ints
    int*   offsets = (int*)(ws + 84131840);              // 8193 ints
    float* payload = (float*)(ws + 84164624);            // 65536*8 floats = 2 MB

    // ---- binning (counts+cursor zeroed each call; ws is poisoned 0xAA) ----
    zero_ints_kernel<<<(16384 + 255) / 256, 256, 0, stream>>>(counts, 16384); // counts+cursor contiguous
    bin_count_kernel<<<(BATCH * NPART) / 256, 256, 0, stream>>>(locs, counts);
    scan_kernel<<<1, 256, 0, stream>>>(counts, offsets);
    bin_scatter_kernel<<<(BATCH * NPART) / 256, 256, 0, stream>>>(
        locs, data, density, offsets, cursor, payload);

    // ---- weight repack ----
    repack_kernel<<<(14 * 512 + 255) / 256, 256, 0, stream>>>(W0, Bp0, 32,  4,  8, 14);
    repack_kernel<<<(54 * 512 + 255) / 256, 256, 0, stream>>>(W1, Bp1, 32, 32, 32, 54);
    repack_kernel<<<(54 * 512 + 255) / 256, 256, 0, stream>>>(W2, Bp2, 32, 32, 32, 54);
    repack_kernel<<<(54 * 512 + 255) / 256, 256, 0, stream>>>(W3, Bp3,  4, 32, 32, 54);

    // ---- particles -> bf16 grid (cell-owner gather, no atomics) ----
    splat_gather_kernel<<<BATCH * 512, 256, 0, stream>>>(payload, offsets, g8);

    // ---- conv chain ----
    const int CGRID = BATCH * 64 * 32;   // 4096 workgroups
    mfma_conv_kernel< 1, 14, false><<<CGRID, 256, 0, stream>>>(g8, Bp0, b0, a0, gA);
    mfma_conv_kernel< 4, 54, false><<<CGRID, 256, 0, stream>>>(gA, Bp1, b1, a1, gB);
    mfma_conv_kernel< 4, 54, false><<<CGRID, 256, 0, stream>>>(gB, Bp2, b2, a2, gA);
    mfma_conv_kernel< 4, 54, true ><<<CGRID, 256, 0, stream>>>(gA, Bp3, b3, b3, gF);

    // ---- grid -> particles ----
    gather_kernel<<<(BATCH * NPART) / 256, 256, 0, stream>>>(gF, locs, out);
}

// Round 6
// 298.923 us; speedup vs baseline: 2.3620x; 1.1347x over previous
//
#include <hip/hip_runtime.h>

#define BATCH 2
#define NPART 32768
#define GD 64
#define NVOX (BATCH * GD * GD * GD)   // 524288

typedef unsigned short ushortT;
typedef __attribute__((ext_vector_type(8))) short short8;
typedef __attribute__((ext_vector_type(16))) float float16;

__device__ __forceinline__ float poly6_c() {
    const double H9 = 1.0 / 35184372088832.0; // 0.03125^9 == 2^-45 (exact)
    return (float)(315.0 / (64.0 * 3.14159265358979323846 * H9));
}

__device__ __forceinline__ ushortT bf16_rne(float f) {
    unsigned int u = __float_as_uint(f);
    u = (u + 0x7fffu + ((u >> 16) & 1u)) >> 16;   // round-to-nearest-even
    return (ushortT)u;
}

__device__ __forceinline__ int imax(int a, int b) { return a > b ? a : b; }
__device__ __forceinline__ int imin(int a, int b) { return a < b ? a : b; }

// ---------------- zero ints (bin counts + cursors) ----------------
__global__ void zero_ints_kernel(int* __restrict__ p, int n) {
    int t = blockIdx.x * blockDim.x + threadIdx.x;
    if (t < n) p[t] = 0;
}

// ---------------- bin count: particle -> 2^3-cell bin histogram ----------------
// fine bins: 32x32x32 per batch = 32768; bin idx = ((bx*32)+by)*32+bz, bx=x>>1
__global__ __launch_bounds__(256) void bin_count_kernel(
    const float* __restrict__ locs, int* __restrict__ counts) {
    int t = blockIdx.x * blockDim.x + threadIdx.x;
    if (t >= BATCH * NPART) return;
    int b = t >> 15;
    int bx = ((int)floorf(locs[t * 3 + 0] * 64.0f)) >> 1;
    int by = ((int)floorf(locs[t * 3 + 1] * 64.0f)) >> 1;
    int bz = ((int)floorf(locs[t * 3 + 2] * 64.0f)) >> 1;
    atomicAdd(&counts[b * 32768 + ((bx * 32) + by) * 32 + bz], 1);
}

// ---------------- scan, level A: per-256-block exclusive scan ----------------
__global__ __launch_bounds__(256) void scanA_kernel(
    const int* __restrict__ counts, int* __restrict__ offsets,
    int* __restrict__ blockSum) {
    __shared__ int sh[256];
    int tid = threadIdx.x, g = blockIdx.x;        // 256 blocks x 256
    int v = counts[g * 256 + tid];
    sh[tid] = v;
    __syncthreads();
    for (int off = 1; off < 256; off <<= 1) {
        int u = (tid >= off) ? sh[tid - off] : 0;
        __syncthreads();
        sh[tid] += u;
        __syncthreads();
    }
    offsets[g * 256 + tid] = sh[tid] - v;         // exclusive
    if (tid == 255) blockSum[g] = sh[255];
}

// ---------------- scan, level B: add block prefixes ----------------
__global__ __launch_bounds__(256) void scanB_kernel(
    int* __restrict__ offsets, const int* __restrict__ blockSum) {
    __shared__ int sh[256];
    int tid = threadIdx.x, g = blockIdx.x;
    sh[tid] = (tid < g) ? blockSum[tid] : 0;
    __syncthreads();
    for (int off = 128; off > 0; off >>= 1) {
        if (tid < off) sh[tid] += sh[tid + off];
        __syncthreads();
    }
    offsets[g * 256 + tid] += sh[0];
    if (g == 255 && tid == 255) offsets[65536] = BATCH * NPART;  // sentinel
}

// ---------------- scatter particles into binned payload ----------------
// payload[idx]: {px,py,pz,v0, v1,v2,v3,0}
__global__ __launch_bounds__(256) void bin_scatter_kernel(
    const float* __restrict__ locs, const float* __restrict__ data,
    const float* __restrict__ density, const int* __restrict__ offsets,
    int* __restrict__ cursor, float* __restrict__ payload) {
    int t = blockIdx.x * blockDim.x + threadIdx.x;
    if (t >= BATCH * NPART) return;
    int b = t >> 15;
    float px = locs[t * 3 + 0];
    float py = locs[t * 3 + 1];
    float pz = locs[t * 3 + 2];
    int bx = ((int)floorf(px * 64.0f)) >> 1;
    int by = ((int)floorf(py * 64.0f)) >> 1;
    int bz = ((int)floorf(pz * 64.0f)) >> 1;
    int bb = b * 32768 + ((bx * 32) + by) * 32 + bz;
    int slot = atomicAdd(&cursor[bb], 1);
    int idx = offsets[bb] + slot;
    float inv_d = 1.0f / density[t];
    float4 p0 = {px, py, pz, data[t * 4 + 0] * inv_d};
    float4 p1 = {data[t * 4 + 1] * inv_d, data[t * 4 + 2] * inv_d,
                 data[t * 4 + 3] * inv_d, 0.f};
    *(float4*)(payload + idx * 8)     = p0;
    *(float4*)(payload + idx * 8 + 4) = p1;
}

// ---------------- cell-owner gather splat: no atomics ----------------
// WG owns 8^3 region; thread owns 2 cells (same x,y; z and z+4);
// halo = exact 12^3-cell region via 2^3 bins (<=6x6 xy segments, z-contig).
__global__ __launch_bounds__(256) void splat_gather_kernel(
    const float* __restrict__ payload, const int* __restrict__ offsets,
    ushortT* __restrict__ g8) {
    __shared__ float plist[256 * 8];
    __shared__ int segS[36];
    __shared__ int segP[37];
    __shared__ int shTot[1];

    int wg = blockIdx.x;                          // 1024 = b*512 + sb
    int sb = wg & 511, b = wg >> 9;
    int X0 = (sb >> 6) * 8, Y0 = ((sb >> 3) & 7) * 8, Z0 = (sb & 7) * 8;
    int tid = threadIdx.x;

    int bxlo = imax(0, (X0 - 2) >> 1), bxhi = imin(31, (X0 + 9) >> 1);
    int bylo = imax(0, (Y0 - 2) >> 1), byhi = imin(31, (Y0 + 9) >> 1);
    int bzlo = imax(0, (Z0 - 2) >> 1), bzhi = imin(31, (Z0 + 9) >> 1);
    int ny = byhi - bylo + 1;
    int ns = (bxhi - bxlo + 1) * ny;
    if (tid < ns) {
        int bx = bxlo + tid / ny, by = bylo + tid % ny;
        int row = b * 32768 + (bx * 32 + by) * 32;
        int s = offsets[row + bzlo];
        int e = offsets[row + bzhi + 1];          // z-contiguous in bin order
        segS[tid] = s;
        segP[tid] = e - s;                        // length (prefixed below)
    }
    __syncthreads();
    if (tid == 0) {
        int p = 0;
        for (int k = 0; k < ns; ++k) { int len = segP[k]; segP[k] = p; p += len; }
        segP[ns] = p;
        shTot[0] = p;
    }
    __syncthreads();

    const float step = 0.015625f;
    const float h2 = 0.03125f * 0.03125f;
    const float cc = poly6_c();
    int total = shTot[0];

    // this thread's two cells: wave w covers x-block (w>>1), y-block (w&1)
    int l = tid & 63, w = tid >> 6;
    int cx = X0 + 4 * (w >> 1) + (l >> 4);
    int cy = Y0 + 4 * (w & 1) + ((l >> 2) & 3);
    int cz0 = Z0 + (l & 3);
    float xc  = ((float)cx  + 0.5f) * step;
    float yc  = ((float)cy  + 0.5f) * step;
    float zc0 = ((float)cz0 + 0.5f) * step;
    float zc1 = zc0 + 4.0f * step;

    float a00 = 0.f, a01 = 0.f, a02 = 0.f, a03 = 0.f;
    float a10 = 0.f, a11 = 0.f, a12 = 0.f, a13 = 0.f;

    int nchunks = (total + 255) >> 8;
    for (int ch = 0; ch < nchunks; ++ch) {
        __syncthreads();
        int jj = (ch << 8) + tid;
        if (jj < total) {
            int k = 0;
            while (jj >= segP[k + 1]) ++k;
            int idx = segS[k] + (jj - segP[k]);
            *(float4*)(plist + tid * 8)     = *(const float4*)(payload + idx * 8);
            *(float4*)(plist + tid * 8 + 4) = *(const float4*)(payload + idx * 8 + 4);
        }
        __syncthreads();
        int cnt = imin(256, total - (ch << 8));
        for (int p = 0; p < cnt; ++p) {
            float4 pa = *(const float4*)(plist + p * 8);     // broadcast read
            float dx = pa.x - xc, dy = pa.y - yc;
            float dxy2 = fmaf(dy, dy, dx * dx);
            if (!__any(dxy2 <= h2)) continue;                // wave-coherent skip
            float4 pv = *(const float4*)(plist + p * 8 + 4);
            float dz0 = pa.z - zc0;
            float d20 = fmaf(dz0, dz0, dxy2);
            float u0 = fmaxf(h2 - d20, 0.f);
            float w0 = (cc * u0) * (u0 * u0);
            a00 = fmaf(w0, pa.w, a00);
            a01 = fmaf(w0, pv.x, a01);
            a02 = fmaf(w0, pv.y, a02);
            a03 = fmaf(w0, pv.z, a03);
            float dz1 = pa.z - zc1;
            float d21 = fmaf(dz1, dz1, dxy2);
            float u1 = fmaxf(h2 - d21, 0.f);
            float w1 = (cc * u1) * (u1 * u1);
            a10 = fmaf(w1, pa.w, a10);
            a11 = fmaf(w1, pv.x, a11);
            a12 = fmaf(w1, pv.y, a12);
            a13 = fmaf(w1, pv.z, a13);
        }
    }

    size_t cellBase = (size_t)(((b * 64 + cx) * 64 + cy) * 64);
    short8 o;
    o[0] = (short)bf16_rne(a00); o[1] = (short)bf16_rne(a01);
    o[2] = (short)bf16_rne(a02); o[3] = (short)bf16_rne(a03);
    o[4] = 0; o[5] = 0; o[6] = 0; o[7] = 0;
    *(short8*)(g8 + (cellBase + cz0) * 8) = o;
    o[0] = (short)bf16_rne(a10); o[1] = (short)bf16_rne(a11);
    o[2] = (short)bf16_rne(a12); o[3] = (short)bf16_rne(a13);
    *(short8*)(g8 + (cellBase + cz0 + 4) * 8) = o;
}

// ---------------- fused weight repack into MFMA B-fragment order ----------------
// Bp layout: [kt 0..13]=L0, [14..67]=L1, [68..121]=L2, [122..175]=L3 (contiguous)
__global__ void repack_all_kernel(
    const float* __restrict__ W0, const float* __restrict__ W1,
    const float* __restrict__ W2, const float* __restrict__ W3,
    short* __restrict__ Bp) {
    int t = blockIdx.x * blockDim.x + threadIdx.x;
    if (t >= 176 * 512) return;
    int kt = t >> 9;
    const float* W; int O, I, CINP, ktL;
    if (kt < 14)       { W = W0; O = 32; I = 4;  CINP = 8;  ktL = kt; }
    else if (kt < 68)  { W = W1; O = 32; I = 32; CINP = 32; ktL = kt - 14; }
    else if (kt < 122) { W = W2; O = 32; I = 32; CINP = 32; ktL = kt - 68; }
    else               { W = W3; O = 4;  I = 32; CINP = 32; ktL = kt - 122; }
    int l = (t >> 3) & 63, j = t & 7;
    int n = l & 31, q = l >> 5;
    int k = ktL * 16 + 8 * q + j;
    int tap = k / CINP;
    int ic  = k - tap * CINP;
    float v = 0.f;
    if (tap < 27 && ic < I && n < O) v = W[(n * I + ic) * 27 + tap];
    Bp[t] = (short)bf16_rne(v);
}

// ---------------- MFMA implicit-GEMM 3x3x3 conv (XCD-swizzled) ----------------
template <int ICG, int KT, bool FINAL>
__global__ __launch_bounds__(256) void mfma_conv_kernel(
    const ushortT* __restrict__ in, const short* __restrict__ Bpack,
    const float* __restrict__ bias, const float* __restrict__ alpha,
    void* __restrict__ outv) {
    constexpr int CIN = ICG * 8;
    __shared__ short lds[12 * ICG * 66 * 8];       // [col12][icg][z66][8ch]
    // XCD swizzle: blockIdx%8 = XCD -> give each XCD a contiguous (b,x,yp) slab
    int wg = ((blockIdx.x & 7) << 9) | (blockIdx.x >> 3);   // 4096 tiles
    int yp = wg & 31, x = (wg >> 5) & 63, b = wg >> 11;
    int y0 = yp * 2;
    int tid = threadIdx.x;

    const int NCH = 12 * ICG * 66;                 // 16B chunks
    for (int cc = tid; cc < NCH; cc += 256) {
        int col = cc / (ICG * 66);
        int rem = cc - col * (ICG * 66);
        int icg = rem / 66;
        int z66 = rem - icg * 66;
        int gx = x + (col >> 2) - 1;               // col = dx*4 + ty
        int gy = y0 + (col & 3) - 1;
        int z  = z66 - 1;
        short8 v = short8{0,0,0,0,0,0,0,0};
        if ((unsigned)gx < 64u && (unsigned)gy < 64u && (unsigned)z < 64u)
            v = *(const short8*)(in + ((size_t)(((b * 64 + gx) * 64 + gy) * 64 + z)) * CIN + icg * 8);
        *(short8*)(lds + cc * 8) = v;
    }
    __syncthreads();

    int l = tid & 63, w = tid >> 6;
    int ycol = w >> 1, mz = (w & 1) * 32;
    int n = l & 31, q = l >> 5;

    float bval = FINAL ? (n < 4 ? bias[n] : 0.f) : bias[n];
    float16 acc;
#pragma unroll
    for (int r = 0; r < 16; ++r) acc[r] = bval;

    const short* bp = Bpack + (size_t)l * 8;
    int laneBase = (mz + (l & 31)) * 8;
    int ycolOfs  = ycol * (ICG * 66) * 8;

#pragma unroll
    for (int kt = 0; kt < KT; ++kt) {
        short8 bfrag = *(const short8*)(bp + kt * 512);
        int aofs;
        if constexpr (ICG == 1) {
            int tap0 = kt * 2, tap1 = kt * 2 + 1;
            if (tap1 > 26) tap1 = 26;              // B is zero there; any valid addr
            int dx0 = tap0 / 9, r0 = tap0 - dx0 * 9, dy0 = r0 / 3, dz0 = r0 - dy0 * 3;
            int dx1 = tap1 / 9, r1 = tap1 - dx1 * 9, dy1 = r1 / 3, dz1 = r1 - dy1 * 3;
            int c0 = ((dx0 * 4 + dy0) * 66 + dz0) * 8;
            int c1 = ((dx1 * 4 + dy1) * 66 + dz1) * 8;
            aofs = q ? c1 : c0;
        } else {
            int tap = kt >> 1;
            int dx = tap / 9, rr = tap - dx * 9, dy = rr / 3, dz = rr - dy * 3;
            int icg = (kt & 1) * 2 + q;
            aofs = (((dx * 4 + dy) * ICG + icg) * 66 + dz) * 8;
        }
        short8 afrag = *(const short8*)(lds + aofs + ycolOfs + laneBase);
        acc = __builtin_amdgcn_mfma_f32_32x32x16_bf16(afrag, bfrag, acc, 0, 0, 0);
    }

    int ygl = y0 + ycol;
    size_t base = (size_t)(((b * 64 + x) * 64 + ygl) * 64);
    if (FINAL) {
        float* out = (float*)outv;
        if (n < 4) {
#pragma unroll
            for (int r = 0; r < 16; ++r) {
                int z = mz + (r & 3) + 8 * (r >> 2) + 4 * q;
                out[(base + z) * 4 + n] = acc[r];
            }
        }
    } else {
        float a = alpha[0];
        ushortT* out = (ushortT*)outv;
#pragma unroll
        for (int r = 0; r < 16; ++r) {
            int z = mz + (r & 3) + 8 * (r >> 2) + 4 * q;
            float v = acc[r];
            v = v >= 0.f ? v : a * v;
            out[(base + z) * 32 + n] = bf16_rne(v);
        }
    }
}

// ---------------- grid2particles (trilinear gather, fp32 grid) ----------------
__global__ __launch_bounds__(256) void gather_kernel(
    const float* __restrict__ grid, const float* __restrict__ locs,
    float* __restrict__ out) {
    int t = blockIdx.x * blockDim.x + threadIdx.x;
    if (t >= BATCH * NPART) return;
    int b = t >> 15;

    float px = locs[t * 3 + 0] * 64.0f - 0.5f;
    float py = locs[t * 3 + 1] * 64.0f - 0.5f;
    float pz = locs[t * 3 + 2] * 64.0f - 0.5f;
    int ix = (int)floorf(px);
    int iy = (int)floorf(py);
    int iz = (int)floorf(pz);
    float fx = px - (float)ix;
    float fy = py - (float)iy;
    float fz = pz - (float)iz;

    const float* gb = grid + (size_t)b * GD * GD * GD * 4;
    float o0 = 0.f, o1 = 0.f, o2 = 0.f, o3 = 0.f;

#pragma unroll
    for (int dx = 0; dx < 2; ++dx) {
        int x = ix + dx;
        if ((unsigned)x > 63u) continue;
        float wx = dx ? fx : 1.0f - fx;
#pragma unroll
        for (int dy = 0; dy < 2; ++dy) {
            int y = iy + dy;
            if ((unsigned)y > 63u) continue;
            float wy = dy ? fy : 1.0f - fy;
#pragma unroll
            for (int dz = 0; dz < 2; ++dz) {
                int z = iz + dz;
                if ((unsigned)z > 63u) continue;
                float wz = dz ? fz : 1.0f - fz;
                float w = wx * wy * wz;
                const float4 g = *(const float4*)(gb + (size_t)(((x * GD) + y) * GD + z) * 4);
                o0 += w * g.x; o1 += w * g.y; o2 += w * g.z; o3 += w * g.w;
            }
        }
    }
    out[t * 4 + 0] = o0;
    out[t * 4 + 1] = o1;
    out[t * 4 + 2] = o2;
    out[t * 4 + 3] = o3;
}

extern "C" void kernel_launch(void* const* d_in, const int* in_sizes, int n_in,
                              void* d_out, int out_size, void* d_ws, size_t ws_size,
                              hipStream_t stream) {
    const float* locs    = (const float*)d_in[0];
    const float* data    = (const float*)d_in[1];
    const float* density = (const float*)d_in[2];
    const float* W0 = (const float*)d_in[3];
    const float* b0 = (const float*)d_in[4];
    const float* W1 = (const float*)d_in[5];
    const float* b1 = (const float*)d_in[6];
    const float* W2 = (const float*)d_in[7];
    const float* b2 = (const float*)d_in[8];
    const float* W3 = (const float*)d_in[9];
    const float* b3 = (const float*)d_in[10];
    const float* a0 = (const float*)d_in[11];
    const float* a1 = (const float*)d_in[12];
    const float* a2 = (const float*)d_in[13];
    float* out = (float*)d_out;

    char* ws = (char*)d_ws;
    ushortT* g8  = (ushortT*)(ws);                       // 8 MB bf16 8ch
    ushortT* gA  = (ushortT*)(ws + 8388608);             // 33.5 MB bf16 32ch
    ushortT* gB  = (ushortT*)(ws + 41943040);            // 33.5 MB bf16 32ch
    float*  gF   = (float*)(ws + 75497472);              // 8 MB fp32 4ch
    short*  Bp   = (short*)(ws + 83886080);              // 176*512*2 = 180224 B
    short*  Bp0  = Bp;                                   // kt 0..13
    short*  Bp1  = Bp + 14 * 512;                        // kt 14..67
    short*  Bp2  = Bp + 68 * 512;                        // kt 68..121
    short*  Bp3  = Bp + 122 * 512;                       // kt 122..175
    int*   counts   = (int*)(ws + 84066304);             // 65536 ints
    int*   cursor   = (int*)(ws + 84328448);             // 65536 ints (contig after counts)
    int*   offsets  = (int*)(ws + 84590592);             // 65537 ints
    int*   blockSum = (int*)(ws + 84852752);             // 256 ints
    float* payload  = (float*)(ws + 84853888);           // 65536*8 floats = 2 MB

    // ---- binning ----
    zero_ints_kernel<<<(131072 + 255) / 256, 256, 0, stream>>>(counts, 131072);
    bin_count_kernel<<<(BATCH * NPART) / 256, 256, 0, stream>>>(locs, counts);
    scanA_kernel<<<256, 256, 0, stream>>>(counts, offsets, blockSum);
    scanB_kernel<<<256, 256, 0, stream>>>(offsets, blockSum);
    bin_scatter_kernel<<<(BATCH * NPART) / 256, 256, 0, stream>>>(
        locs, data, density, offsets, cursor, payload);

    // ---- weight repack (fused) ----
    repack_all_kernel<<<(176 * 512 + 255) / 256, 256, 0, stream>>>(W0, W1, W2, W3, Bp);

    // ---- particles -> bf16 grid (cell-owner gather, no atomics) ----
    splat_gather_kernel<<<BATCH * 512, 256, 0, stream>>>(payload, offsets, g8);

    // ---- conv chain ----
    const int CGRID = BATCH * 64 * 32;   // 4096 workgroups
    mfma_conv_kernel< 1, 14, false><<<CGRID, 256, 0, stream>>>(g8, Bp0, b0, a0, gA);
    mfma_conv_kernel< 4, 54, false><<<CGRID, 256, 0, stream>>>(gA, Bp1, b1, a1, gB);
    mfma_conv_kernel< 4, 54, false><<<CGRID, 256, 0, stream>>>(gB, Bp2, b2, a2, gA);
    mfma_conv_kernel< 4, 54, true ><<<CGRID, 256, 0, stream>>>(gA, Bp3, b3, b3, gF);

    // ---- grid -> particles ----
    gather_kernel<<<(BATCH * NPART) / 256, 256, 0, stream>>>(gF, locs, out);
}

// Round 7
// 267.096 us; speedup vs baseline: 2.6435x; 1.1192x over previous
//
#include <hip/hip_runtime.h>

#define BATCH 2
#define NPART 32768
#define GD 64
#define NVOX (BATCH * GD * GD * GD)   // 524288

typedef unsigned short ushortT;
typedef __attribute__((ext_vector_type(8))) short short8;
typedef __attribute__((ext_vector_type(16))) float float16;

__device__ __forceinline__ float poly6_c() {
    const double H9 = 1.0 / 35184372088832.0; // 0.03125^9 == 2^-45 (exact)
    return (float)(315.0 / (64.0 * 3.14159265358979323846 * H9));
}

__device__ __forceinline__ ushortT bf16_rne(float f) {
    unsigned int u = __float_as_uint(f);
    u = (u + 0x7fffu + ((u >> 16) & 1u)) >> 16;   // round-to-nearest-even
    return (ushortT)u;
}

__device__ __forceinline__ int imax(int a, int b) { return a > b ? a : b; }
__device__ __forceinline__ int imin(int a, int b) { return a < b ? a : b; }

// async global->LDS, 16 B per lane; LDS dest = wave-uniform base + lane*16
__device__ __forceinline__ void load_lds16(const void* g, void* l) {
    __builtin_amdgcn_global_load_lds(
        (const __attribute__((address_space(1))) void*)g,
        (__attribute__((address_space(3))) void*)l, 16, 0, 0);
}

// ---------------- zero ints (zguard + bin counts + cursors) ----------------
__global__ void zero_ints_kernel(int* __restrict__ p, int n) {
    int t = blockIdx.x * blockDim.x + threadIdx.x;
    if (t < n) p[t] = 0;
}

// ---------------- bin count: particle -> 2^3-cell bin histogram ----------------
__global__ __launch_bounds__(256) void bin_count_kernel(
    const float* __restrict__ locs, int* __restrict__ counts) {
    int t = blockIdx.x * blockDim.x + threadIdx.x;
    if (t >= BATCH * NPART) return;
    int b = t >> 15;
    int bx = ((int)floorf(locs[t * 3 + 0] * 64.0f)) >> 1;
    int by = ((int)floorf(locs[t * 3 + 1] * 64.0f)) >> 1;
    int bz = ((int)floorf(locs[t * 3 + 2] * 64.0f)) >> 1;
    atomicAdd(&counts[b * 32768 + ((bx * 32) + by) * 32 + bz], 1);
}

// ---------------- scan, level A: per-256-block exclusive scan ----------------
__global__ __launch_bounds__(256) void scanA_kernel(
    const int* __restrict__ counts, int* __restrict__ offsets,
    int* __restrict__ blockSum) {
    __shared__ int sh[256];
    int tid = threadIdx.x, g = blockIdx.x;        // 256 blocks x 256
    int v = counts[g * 256 + tid];
    sh[tid] = v;
    __syncthreads();
    for (int off = 1; off < 256; off <<= 1) {
        int u = (tid >= off) ? sh[tid - off] : 0;
        __syncthreads();
        sh[tid] += u;
        __syncthreads();
    }
    offsets[g * 256 + tid] = sh[tid] - v;         // exclusive
    if (tid == 255) blockSum[g] = sh[255];
}

// ---------------- scan, level B: add block prefixes ----------------
__global__ __launch_bounds__(256) void scanB_kernel(
    int* __restrict__ offsets, const int* __restrict__ blockSum) {
    __shared__ int sh[256];
    int tid = threadIdx.x, g = blockIdx.x;
    sh[tid] = (tid < g) ? blockSum[tid] : 0;
    __syncthreads();
    for (int off = 128; off > 0; off >>= 1) {
        if (tid < off) sh[tid] += sh[tid + off];
        __syncthreads();
    }
    offsets[g * 256 + tid] += sh[0];
    if (g == 255 && tid == 255) offsets[65536] = BATCH * NPART;  // sentinel
}

// ---------------- scatter particles into binned payload ----------------
__global__ __launch_bounds__(256) void bin_scatter_kernel(
    const float* __restrict__ locs, const float* __restrict__ data,
    const float* __restrict__ density, const int* __restrict__ offsets,
    int* __restrict__ cursor, float* __restrict__ payload) {
    int t = blockIdx.x * blockDim.x + threadIdx.x;
    if (t >= BATCH * NPART) return;
    int b = t >> 15;
    float px = locs[t * 3 + 0];
    float py = locs[t * 3 + 1];
    float pz = locs[t * 3 + 2];
    int bx = ((int)floorf(px * 64.0f)) >> 1;
    int by = ((int)floorf(py * 64.0f)) >> 1;
    int bz = ((int)floorf(pz * 64.0f)) >> 1;
    int bb = b * 32768 + ((bx * 32) + by) * 32 + bz;
    int slot = atomicAdd(&cursor[bb], 1);
    int idx = offsets[bb] + slot;
    float inv_d = 1.0f / density[t];
    float4 p0 = {px, py, pz, data[t * 4 + 0] * inv_d};
    float4 p1 = {data[t * 4 + 1] * inv_d, data[t * 4 + 2] * inv_d,
                 data[t * 4 + 3] * inv_d, 0.f};
    *(float4*)(payload + idx * 8)     = p0;
    *(float4*)(payload + idx * 8 + 4) = p1;
}

// ---------------- cell-owner gather splat: no atomics ----------------
__global__ __launch_bounds__(256) void splat_gather_kernel(
    const float* __restrict__ payload, const int* __restrict__ offsets,
    ushortT* __restrict__ g8) {
    __shared__ float plist[256 * 8];
    __shared__ int segS[36];
    __shared__ int segP[37];
    __shared__ int shTot[1];

    int wg = blockIdx.x;                          // 1024 = b*512 + sb
    int sb = wg & 511, b = wg >> 9;
    int X0 = (sb >> 6) * 8, Y0 = ((sb >> 3) & 7) * 8, Z0 = (sb & 7) * 8;
    int tid = threadIdx.x;

    int bxlo = imax(0, (X0 - 2) >> 1), bxhi = imin(31, (X0 + 9) >> 1);
    int bylo = imax(0, (Y0 - 2) >> 1), byhi = imin(31, (Y0 + 9) >> 1);
    int bzlo = imax(0, (Z0 - 2) >> 1), bzhi = imin(31, (Z0 + 9) >> 1);
    int ny = byhi - bylo + 1;
    int ns = (bxhi - bxlo + 1) * ny;
    if (tid < ns) {
        int bx = bxlo + tid / ny, by = bylo + tid % ny;
        int row = b * 32768 + (bx * 32 + by) * 32;
        int s = offsets[row + bzlo];
        int e = offsets[row + bzhi + 1];
        segS[tid] = s;
        segP[tid] = e - s;
    }
    __syncthreads();
    if (tid == 0) {
        int p = 0;
        for (int k = 0; k < ns; ++k) { int len = segP[k]; segP[k] = p; p += len; }
        segP[ns] = p;
        shTot[0] = p;
    }
    __syncthreads();

    const float step = 0.015625f;
    const float h2 = 0.03125f * 0.03125f;
    const float cc = poly6_c();
    int total = shTot[0];

    int l = tid & 63, w = tid >> 6;
    int cx = X0 + 4 * (w >> 1) + (l >> 4);
    int cy = Y0 + 4 * (w & 1) + ((l >> 2) & 3);
    int cz0 = Z0 + (l & 3);
    float xc  = ((float)cx  + 0.5f) * step;
    float yc  = ((float)cy  + 0.5f) * step;
    float zc0 = ((float)cz0 + 0.5f) * step;
    float zc1 = zc0 + 4.0f * step;

    float a00 = 0.f, a01 = 0.f, a02 = 0.f, a03 = 0.f;
    float a10 = 0.f, a11 = 0.f, a12 = 0.f, a13 = 0.f;

    int nchunks = (total + 255) >> 8;
    for (int ch = 0; ch < nchunks; ++ch) {
        __syncthreads();
        int jj = (ch << 8) + tid;
        if (jj < total) {
            int k = 0;
            while (jj >= segP[k + 1]) ++k;
            int idx = segS[k] + (jj - segP[k]);
            *(float4*)(plist + tid * 8)     = *(const float4*)(payload + idx * 8);
            *(float4*)(plist + tid * 8 + 4) = *(const float4*)(payload + idx * 8 + 4);
        }
        __syncthreads();
        int cnt = imin(256, total - (ch << 8));
        for (int p = 0; p < cnt; ++p) {
            float4 pa = *(const float4*)(plist + p * 8);     // broadcast read
            float dx = pa.x - xc, dy = pa.y - yc;
            float dxy2 = fmaf(dy, dy, dx * dx);
            if (!__any(dxy2 <= h2)) continue;                // wave-coherent skip
            float4 pv = *(const float4*)(plist + p * 8 + 4);
            float dz0 = pa.z - zc0;
            float d20 = fmaf(dz0, dz0, dxy2);
            float u0 = fmaxf(h2 - d20, 0.f);
            float w0 = (cc * u0) * (u0 * u0);
            a00 = fmaf(w0, pa.w, a00);
            a01 = fmaf(w0, pv.x, a01);
            a02 = fmaf(w0, pv.y, a02);
            a03 = fmaf(w0, pv.z, a03);
            float dz1 = pa.z - zc1;
            float d21 = fmaf(dz1, dz1, dxy2);
            float u1 = fmaxf(h2 - d21, 0.f);
            float w1 = (cc * u1) * (u1 * u1);
            a10 = fmaf(w1, pa.w, a10);
            a11 = fmaf(w1, pv.x, a11);
            a12 = fmaf(w1, pv.y, a12);
            a13 = fmaf(w1, pv.z, a13);
        }
    }

    size_t cellBase = (size_t)(((b * 64 + cx) * 64 + cy) * 64);
    short8 o;
    o[0] = (short)bf16_rne(a00); o[1] = (short)bf16_rne(a01);
    o[2] = (short)bf16_rne(a02); o[3] = (short)bf16_rne(a03);
    o[4] = 0; o[5] = 0; o[6] = 0; o[7] = 0;
    *(short8*)(g8 + (cellBase + cz0) * 8) = o;
    o[0] = (short)bf16_rne(a10); o[1] = (short)bf16_rne(a11);
    o[2] = (short)bf16_rne(a12); o[3] = (short)bf16_rne(a13);
    *(short8*)(g8 + (cellBase + cz0 + 4) * 8) = o;
}

// ---------------- fused weight repack into MFMA B-fragment order ----------------
__global__ void repack_all_kernel(
    const float* __restrict__ W0, const float* __restrict__ W1,
    const float* __restrict__ W2, const float* __restrict__ W3,
    short* __restrict__ Bp) {
    int t = blockIdx.x * blockDim.x + threadIdx.x;
    if (t >= 176 * 512) return;
    int kt = t >> 9;
    const float* W; int O, I, CINP, ktL;
    if (kt < 14)       { W = W0; O = 32; I = 4;  CINP = 8;  ktL = kt; }
    else if (kt < 68)  { W = W1; O = 32; I = 32; CINP = 32; ktL = kt - 14; }
    else if (kt < 122) { W = W2; O = 32; I = 32; CINP = 32; ktL = kt - 68; }
    else               { W = W3; O = 4;  I = 32; CINP = 32; ktL = kt - 122; }
    int l = (t >> 3) & 63, j = t & 7;
    int n = l & 31, q = l >> 5;
    int k = ktL * 16 + 8 * q + j;
    int tap = k / CINP;
    int ic  = k - tap * CINP;
    float v = 0.f;
    if (tap < 27 && ic < I && n < O) v = W[(n * I + ic) * 27 + tap];
    Bp[t] = (short)bf16_rne(v);
}

// ---------------- MFMA implicit-GEMM 3x3x3 conv ----------------
// WG owns 2x2 columns x 32-z half; halo 4x4 cols x 34 z staged via
// global_load_lds (OOB -> zguard). LDS layout [col16][icg][z34][8ch].
template <int ICG, int KT, bool FINAL>
__global__ __launch_bounds__(256) void mfma_conv_kernel(
    const ushortT* __restrict__ in, const short* __restrict__ Bpack,
    const float* __restrict__ bias, const float* __restrict__ alpha,
    const float* __restrict__ zguard, void* __restrict__ outv) {
    constexpr int CIN = ICG * 8;
    constexpr int NCH = 16 * ICG * 34;             // 16 B chunks
    __shared__ short lds[NCH * 8];
    // XCD swizzle: contiguous (b,xp,yp,zh) slab per XCD
    int wg = ((blockIdx.x & 7) << 9) | (blockIdx.x >> 3);   // 4096
    int zh = wg & 1, yp = (wg >> 1) & 31, xp = (wg >> 6) & 31, b = wg >> 11;
    int X0 = xp * 2, Y0 = yp * 2, Z0 = zh * 32;
    int tid = threadIdx.x;

    const ushortT* inb = in + (size_t)b * (64 * 64 * 64 * CIN);
#pragma unroll
    for (int it = 0; it < (NCH + 255) / 256; ++it) {
        int ccid = it * 256 + tid;
        if (ccid < NCH) {
            int col = ccid / (ICG * 34);
            int rem = ccid - col * (ICG * 34);
            int icg = rem / 34;
            int zi  = rem - icg * 34;
            int gx = X0 + (col >> 2) - 1;
            int gy = Y0 + (col & 3) - 1;
            int gz = Z0 + zi - 1;
            const void* src = (const void*)zguard;
            if ((unsigned)gx < 64u && (unsigned)gy < 64u && (unsigned)gz < 64u)
                src = (const void*)(inb + ((size_t)(((gx * 64) + gy) * 64 + gz)) * CIN + icg * 8);
            load_lds16(src, (void*)(lds + ccid * 8));
        }
    }
    __syncthreads();   // drains vmcnt (global_load_lds) + barrier

    int l = tid & 63, w = tid >> 6;
    int wx = w >> 1, wy = w & 1;                   // owned column in 2x2
    int n = l & 31, q = l >> 5;

    float bval = FINAL ? (n < 4 ? bias[n] : 0.f) : bias[n];
    float16 acc;
#pragma unroll
    for (int r = 0; r < 16; ++r) acc[r] = bval;

    const short* bp = Bpack + (size_t)l * 8;
    int laneZ = (l & 31) * 8;                      // z-row offset (shorts)

#pragma unroll
    for (int kt = 0; kt < KT; ++kt) {
        short8 bfrag = *(const short8*)(bp + kt * 512);
        int aofs;
        if constexpr (ICG == 1) {
            int tap0 = kt * 2, tap1 = kt * 2 + 1;
            if (tap1 > 26) tap1 = 26;              // B is zero there
            int dx0 = tap0 / 9, r0 = tap0 - dx0 * 9, dy0 = r0 / 3, dz0 = r0 - dy0 * 3;
            int dx1 = tap1 / 9, r1 = tap1 - dx1 * 9, dy1 = r1 / 3, dz1 = r1 - dy1 * 3;
            int c0 = (((wx + dx0) * 4 + (wy + dy0)) * 34 + dz0) * 8;
            int c1 = (((wx + dx1) * 4 + (wy + dy1)) * 34 + dz1) * 8;
            aofs = q ? c1 : c0;
        } else {
            int tap = kt >> 1;
            int dx = tap / 9, rr = tap - dx * 9, dy = rr / 3, dz = rr - dy * 3;
            int icg = (kt & 1) * 2 + q;
            aofs = ((((wx + dx) * 4 + (wy + dy)) * ICG + icg) * 34 + dz) * 8;
        }
        short8 afrag = *(const short8*)(lds + aofs + laneZ);
        acc = __builtin_amdgcn_mfma_f32_32x32x16_bf16(afrag, bfrag, acc, 0, 0, 0);
    }

    size_t base = (size_t)(((b * 64 + X0 + wx) * 64 + (Y0 + wy)) * 64) + Z0;
    if (FINAL) {
        float* out = (float*)outv;
        if (n < 4) {
#pragma unroll
            for (int r = 0; r < 16; ++r) {
                int z = (r & 3) + 8 * (r >> 2) + 4 * q;
                out[(base + z) * 4 + n] = acc[r];
            }
        }
    } else {
        float a = alpha[0];
        ushortT* out = (ushortT*)outv;
#pragma unroll
        for (int r = 0; r < 16; ++r) {
            int z = (r & 3) + 8 * (r >> 2) + 4 * q;
            float v = acc[r];
            v = v >= 0.f ? v : a * v;
            out[(base + z) * 32 + n] = bf16_rne(v);
        }
    }
}

// ---------------- grid2particles (trilinear gather, fp32 grid) ----------------
__global__ __launch_bounds__(256) void gather_kernel(
    const float* __restrict__ grid, const float* __restrict__ locs,
    float* __restrict__ out) {
    int t = blockIdx.x * blockDim.x + threadIdx.x;
    if (t >= BATCH * NPART) return;
    int b = t >> 15;

    float px = locs[t * 3 + 0] * 64.0f - 0.5f;
    float py = locs[t * 3 + 1] * 64.0f - 0.5f;
    float pz = locs[t * 3 + 2] * 64.0f - 0.5f;
    int ix = (int)floorf(px);
    int iy = (int)floorf(py);
    int iz = (int)floorf(pz);
    float fx = px - (float)ix;
    float fy = py - (float)iy;
    float fz = pz - (float)iz;

    const float* gb = grid + (size_t)b * GD * GD * GD * 4;
    float o0 = 0.f, o1 = 0.f, o2 = 0.f, o3 = 0.f;

#pragma unroll
    for (int dx = 0; dx < 2; ++dx) {
        int x = ix + dx;
        if ((unsigned)x > 63u) continue;
        float wx = dx ? fx : 1.0f - fx;
#pragma unroll
        for (int dy = 0; dy < 2; ++dy) {
            int y = iy + dy;
            if ((unsigned)y > 63u) continue;
            float wy = dy ? fy : 1.0f - fy;
#pragma unroll
            for (int dz = 0; dz < 2; ++dz) {
                int z = iz + dz;
                if ((unsigned)z > 63u) continue;
                float wz = dz ? fz : 1.0f - fz;
                float w = wx * wy * wz;
                const float4 g = *(const float4*)(gb + (size_t)(((x * GD) + y) * GD + z) * 4);
                o0 += w * g.x; o1 += w * g.y; o2 += w * g.z; o3 += w * g.w;
            }
        }
    }
    out[t * 4 + 0] = o0;
    out[t * 4 + 1] = o1;
    out[t * 4 + 2] = o2;
    out[t * 4 + 3] = o3;
}

extern "C" void kernel_launch(void* const* d_in, const int* in_sizes, int n_in,
                              void* d_out, int out_size, void* d_ws, size_t ws_size,
                              hipStream_t stream) {
    const float* locs    = (const float*)d_in[0];
    const float* data    = (const float*)d_in[1];
    const float* density = (const float*)d_in[2];
    const float* W0 = (const float*)d_in[3];
    const float* b0 = (const float*)d_in[4];
    const float* W1 = (const float*)d_in[5];
    const float* b1 = (const float*)d_in[6];
    const float* W2 = (const float*)d_in[7];
    const float* b2 = (const float*)d_in[8];
    const float* W3 = (const float*)d_in[9];
    const float* b3 = (const float*)d_in[10];
    const float* a0 = (const float*)d_in[11];
    const float* a1 = (const float*)d_in[12];
    const float* a2 = (const float*)d_in[13];
    float* out = (float*)d_out;

    char* ws = (char*)d_ws;
    ushortT* g8  = (ushortT*)(ws);                       // 8 MB bf16 8ch
    ushortT* gA  = (ushortT*)(ws + 8388608);             // 33.5 MB bf16 32ch
    ushortT* gB  = (ushortT*)(ws + 41943040);            // 33.5 MB bf16 32ch
    float*  gF   = (float*)(ws + 75497472);              // 8 MB fp32 4ch
    short*  Bp   = (short*)(ws + 83886080);              // 176*512*2 = 180224 B
    short*  Bp0  = Bp;                                   // kt 0..13
    short*  Bp1  = Bp + 14 * 512;                        // kt 14..67
    short*  Bp2  = Bp + 68 * 512;                        // kt 68..121
    short*  Bp3  = Bp + 122 * 512;                       // kt 122..175
    float* zguard   = (float*)(ws + 84066240);           // 64 B zeros (16 ints)
    int*   counts   = (int*)(ws + 84066304);             // 65536 ints
    int*   cursor   = (int*)(ws + 84328448);             // 65536 ints
    int*   offsets  = (int*)(ws + 84590592);             // 65537 ints
    int*   blockSum = (int*)(ws + 84852752);             // 256 ints
    float* payload  = (float*)(ws + 84853888);           // 65536*8 floats = 2 MB

    // ---- zero zguard + counts + cursor (contiguous from zguard) ----
    zero_ints_kernel<<<(131088 + 255) / 256, 256, 0, stream>>>((int*)zguard, 131088);
    bin_count_kernel<<<(BATCH * NPART) / 256, 256, 0, stream>>>(locs, counts);
    scanA_kernel<<<256, 256, 0, stream>>>(counts, offsets, blockSum);
    scanB_kernel<<<256, 256, 0, stream>>>(offsets, blockSum);
    bin_scatter_kernel<<<(BATCH * NPART) / 256, 256, 0, stream>>>(
        locs, data, density, offsets, cursor, payload);

    // ---- weight repack (fused) ----
    repack_all_kernel<<<(176 * 512 + 255) / 256, 256, 0, stream>>>(W0, W1, W2, W3, Bp);

    // ---- particles -> bf16 grid (cell-owner gather, no atomics) ----
    splat_gather_kernel<<<BATCH * 512, 256, 0, stream>>>(payload, offsets, g8);

    // ---- conv chain ----
    const int CGRID = 4096;   // 2 b x 32 xp x 32 yp x 2 zh
    mfma_conv_kernel< 1, 14, false><<<CGRID, 256, 0, stream>>>(g8, Bp0, b0, a0, zguard, gA);
    mfma_conv_kernel< 4, 54, false><<<CGRID, 256, 0, stream>>>(gA, Bp1, b1, a1, zguard, gB);
    mfma_conv_kernel< 4, 54, false><<<CGRID, 256, 0, stream>>>(gB, Bp2, b2, a2, zguard, gA);
    mfma_conv_kernel< 4, 54, true ><<<CGRID, 256, 0, stream>>>(gA, Bp3, b3, b3, zguard, gF);

    // ---- grid -> particles ----
    gather_kernel<<<(BATCH * NPART) / 256, 256, 0, stream>>>(gF, locs, out);
}

// Round 8
// 252.558 us; speedup vs baseline: 2.7956x; 1.0576x over previous
//
#include <hip/hip_runtime.h>

#define BATCH 2
#define NPART 32768
#define GD 64
#define NVOX (BATCH * GD * GD * GD)   // 524288

typedef unsigned short ushortT;
typedef __attribute__((ext_vector_type(8))) short short8;
typedef __attribute__((ext_vector_type(16))) float float16;

__device__ __forceinline__ float poly6_c() {
    const double H9 = 1.0 / 35184372088832.0; // 0.03125^9 == 2^-45 (exact)
    return (float)(315.0 / (64.0 * 3.14159265358979323846 * H9));
}

__device__ __forceinline__ ushortT bf16_rne(float f) {
    unsigned int u = __float_as_uint(f);
    u = (u + 0x7fffu + ((u >> 16) & 1u)) >> 16;   // round-to-nearest-even
    return (ushortT)u;
}

__device__ __forceinline__ int imax(int a, int b) { return a > b ? a : b; }
__device__ __forceinline__ int imin(int a, int b) { return a < b ? a : b; }

// async global->LDS, 16 B per lane; LDS dest = wave-uniform base + lane*16
__device__ __forceinline__ void load_lds16(const void* g, void* l) {
    __builtin_amdgcn_global_load_lds(
        (const __attribute__((address_space(1))) void*)g,
        (__attribute__((address_space(3))) void*)l, 16, 0, 0);
}

// ---------------- zero ints (zguard + bin counts + cursors) ----------------
__global__ void zero_ints_kernel(int* __restrict__ p, int n) {
    int t = blockIdx.x * blockDim.x + threadIdx.x;
    if (t < n) p[t] = 0;
}

// ---------------- bin count: particle -> 2^3-cell bin histogram ----------------
__global__ __launch_bounds__(256) void bin_count_kernel(
    const float* __restrict__ locs, int* __restrict__ counts) {
    int t = blockIdx.x * blockDim.x + threadIdx.x;
    if (t >= BATCH * NPART) return;
    int b = t >> 15;
    int bx = ((int)floorf(locs[t * 3 + 0] * 64.0f)) >> 1;
    int by = ((int)floorf(locs[t * 3 + 1] * 64.0f)) >> 1;
    int bz = ((int)floorf(locs[t * 3 + 2] * 64.0f)) >> 1;
    atomicAdd(&counts[b * 32768 + ((bx * 32) + by) * 32 + bz], 1);
}

// ---------------- scan, level A: per-256-block exclusive scan ----------------
__global__ __launch_bounds__(256) void scanA_kernel(
    const int* __restrict__ counts, int* __restrict__ offsets,
    int* __restrict__ blockSum) {
    __shared__ int sh[256];
    int tid = threadIdx.x, g = blockIdx.x;        // 256 blocks x 256
    int v = counts[g * 256 + tid];
    sh[tid] = v;
    __syncthreads();
    for (int off = 1; off < 256; off <<= 1) {
        int u = (tid >= off) ? sh[tid - off] : 0;
        __syncthreads();
        sh[tid] += u;
        __syncthreads();
    }
    offsets[g * 256 + tid] = sh[tid] - v;         // exclusive
    if (tid == 255) blockSum[g] = sh[255];
}

// ---------------- scan, level B: add block prefixes ----------------
__global__ __launch_bounds__(256) void scanB_kernel(
    int* __restrict__ offsets, const int* __restrict__ blockSum) {
    __shared__ int sh[256];
    int tid = threadIdx.x, g = blockIdx.x;
    sh[tid] = (tid < g) ? blockSum[tid] : 0;
    __syncthreads();
    for (int off = 128; off > 0; off >>= 1) {
        if (tid < off) sh[tid] += sh[tid + off];
        __syncthreads();
    }
    offsets[g * 256 + tid] += sh[0];
    if (g == 255 && tid == 255) offsets[65536] = BATCH * NPART;  // sentinel
}

// ---------------- scatter particles into binned payload ----------------
__global__ __launch_bounds__(256) void bin_scatter_kernel(
    const float* __restrict__ locs, const float* __restrict__ data,
    const float* __restrict__ density, const int* __restrict__ offsets,
    int* __restrict__ cursor, float* __restrict__ payload) {
    int t = blockIdx.x * blockDim.x + threadIdx.x;
    if (t >= BATCH * NPART) return;
    int b = t >> 15;
    float px = locs[t * 3 + 0];
    float py = locs[t * 3 + 1];
    float pz = locs[t * 3 + 2];
    int bx = ((int)floorf(px * 64.0f)) >> 1;
    int by = ((int)floorf(py * 64.0f)) >> 1;
    int bz = ((int)floorf(pz * 64.0f)) >> 1;
    int bb = b * 32768 + ((bx * 32) + by) * 32 + bz;
    int slot = atomicAdd(&cursor[bb], 1);
    int idx = offsets[bb] + slot;
    float inv_d = 1.0f / density[t];
    float4 p0 = {px, py, pz, data[t * 4 + 0] * inv_d};
    float4 p1 = {data[t * 4 + 1] * inv_d, data[t * 4 + 2] * inv_d,
                 data[t * 4 + 3] * inv_d, 0.f};
    *(float4*)(payload + idx * 8)     = p0;
    *(float4*)(payload + idx * 8 + 4) = p1;
}

// ---------------- cell-owner gather splat: no atomics ----------------
__global__ __launch_bounds__(256) void splat_gather_kernel(
    const float* __restrict__ payload, const int* __restrict__ offsets,
    ushortT* __restrict__ g8) {
    __shared__ float plist[256 * 8];
    __shared__ int segS[36];
    __shared__ int segP[37];
    __shared__ int shTot[1];

    int wg = blockIdx.x;                          // 1024 = b*512 + sb
    int sb = wg & 511, b = wg >> 9;
    int X0 = (sb >> 6) * 8, Y0 = ((sb >> 3) & 7) * 8, Z0 = (sb & 7) * 8;
    int tid = threadIdx.x;

    int bxlo = imax(0, (X0 - 2) >> 1), bxhi = imin(31, (X0 + 9) >> 1);
    int bylo = imax(0, (Y0 - 2) >> 1), byhi = imin(31, (Y0 + 9) >> 1);
    int bzlo = imax(0, (Z0 - 2) >> 1), bzhi = imin(31, (Z0 + 9) >> 1);
    int ny = byhi - bylo + 1;
    int ns = (bxhi - bxlo + 1) * ny;
    if (tid < ns) {
        int bx = bxlo + tid / ny, by = bylo + tid % ny;
        int row = b * 32768 + (bx * 32 + by) * 32;
        int s = offsets[row + bzlo];
        int e = offsets[row + bzhi + 1];
        segS[tid] = s;
        segP[tid] = e - s;
    }
    __syncthreads();
    if (tid == 0) {
        int p = 0;
        for (int k = 0; k < ns; ++k) { int len = segP[k]; segP[k] = p; p += len; }
        segP[ns] = p;
        shTot[0] = p;
    }
    __syncthreads();

    const float step = 0.015625f;
    const float h2 = 0.03125f * 0.03125f;
    const float cc = poly6_c();
    int total = shTot[0];

    int l = tid & 63, w = tid >> 6;
    int cx = X0 + 4 * (w >> 1) + (l >> 4);
    int cy = Y0 + 4 * (w & 1) + ((l >> 2) & 3);
    int cz0 = Z0 + (l & 3);
    float xc  = ((float)cx  + 0.5f) * step;
    float yc  = ((float)cy  + 0.5f) * step;
    float zc0 = ((float)cz0 + 0.5f) * step;
    float zc1 = zc0 + 4.0f * step;

    float a00 = 0.f, a01 = 0.f, a02 = 0.f, a03 = 0.f;
    float a10 = 0.f, a11 = 0.f, a12 = 0.f, a13 = 0.f;

    int nchunks = (total + 255) >> 8;
    for (int ch = 0; ch < nchunks; ++ch) {
        __syncthreads();
        int jj = (ch << 8) + tid;
        if (jj < total) {
            int k = 0;
            while (jj >= segP[k + 1]) ++k;
            int idx = segS[k] + (jj - segP[k]);
            *(float4*)(plist + tid * 8)     = *(const float4*)(payload + idx * 8);
            *(float4*)(plist + tid * 8 + 4) = *(const float4*)(payload + idx * 8 + 4);
        }
        __syncthreads();
        int cnt = imin(256, total - (ch << 8));
        for (int p = 0; p < cnt; ++p) {
            float4 pa = *(const float4*)(plist + p * 8);     // broadcast read
            float dx = pa.x - xc, dy = pa.y - yc;
            float dxy2 = fmaf(dy, dy, dx * dx);
            if (!__any(dxy2 <= h2)) continue;                // wave-coherent skip
            float4 pv = *(const float4*)(plist + p * 8 + 4);
            float dz0 = pa.z - zc0;
            float d20 = fmaf(dz0, dz0, dxy2);
            float u0 = fmaxf(h2 - d20, 0.f);
            float w0 = (cc * u0) * (u0 * u0);
            a00 = fmaf(w0, pa.w, a00);
            a01 = fmaf(w0, pv.x, a01);
            a02 = fmaf(w0, pv.y, a02);
            a03 = fmaf(w0, pv.z, a03);
            float dz1 = pa.z - zc1;
            float d21 = fmaf(dz1, dz1, dxy2);
            float u1 = fmaxf(h2 - d21, 0.f);
            float w1 = (cc * u1) * (u1 * u1);
            a10 = fmaf(w1, pa.w, a10);
            a11 = fmaf(w1, pv.x, a11);
            a12 = fmaf(w1, pv.y, a12);
            a13 = fmaf(w1, pv.z, a13);
        }
    }

    size_t cellBase = (size_t)(((b * 64 + cx) * 64 + cy) * 64);
    short8 o;
    o[0] = (short)bf16_rne(a00); o[1] = (short)bf16_rne(a01);
    o[2] = (short)bf16_rne(a02); o[3] = (short)bf16_rne(a03);
    o[4] = 0; o[5] = 0; o[6] = 0; o[7] = 0;
    *(short8*)(g8 + (cellBase + cz0) * 8) = o;
    o[0] = (short)bf16_rne(a10); o[1] = (short)bf16_rne(a11);
    o[2] = (short)bf16_rne(a12); o[3] = (short)bf16_rne(a13);
    *(short8*)(g8 + (cellBase + cz0 + 4) * 8) = o;
}

// ---------------- fused weight repack into MFMA B-fragment order ----------------
__global__ void repack_all_kernel(
    const float* __restrict__ W0, const float* __restrict__ W1,
    const float* __restrict__ W2, const float* __restrict__ W3,
    short* __restrict__ Bp) {
    int t = blockIdx.x * blockDim.x + threadIdx.x;
    if (t >= 176 * 512) return;
    int kt = t >> 9;
    const float* W; int O, I, CINP, ktL;
    if (kt < 14)       { W = W0; O = 32; I = 4;  CINP = 8;  ktL = kt; }
    else if (kt < 68)  { W = W1; O = 32; I = 32; CINP = 32; ktL = kt - 14; }
    else if (kt < 122) { W = W2; O = 32; I = 32; CINP = 32; ktL = kt - 68; }
    else               { W = W3; O = 4;  I = 32; CINP = 32; ktL = kt - 122; }
    int l = (t >> 3) & 63, j = t & 7;
    int n = l & 31, q = l >> 5;
    int k = ktL * 16 + 8 * q + j;
    int tap = k / CINP;
    int ic  = k - tap * CINP;
    float v = 0.f;
    if (tap < 27 && ic < I && n < O) v = W[(n * I + ic) * 27 + tap];
    Bp[t] = (short)bf16_rne(v);
}

// ---------------- MFMA implicit-GEMM 3x3x3 conv ----------------
// WG owns 2x4 columns x 32-z half (256 voxels); wave owns 2 adjacent-y cols
// (B-fragment reuse x2, 2 accumulators). Halo 4x6 cols x 34 z staged via
// global_load_lds (OOB -> zguard). LDS layout [cx4][cy6][icg][z34][8ch].
// Depth-4 rolling B-prefetch hides the per-kt global B latency.
template <int ICG, int KT, bool FINAL>
__global__ __launch_bounds__(256, 3) void mfma_conv_kernel(
    const ushortT* __restrict__ in, const short* __restrict__ Bpack,
    const float* __restrict__ bias, const float* __restrict__ alpha,
    const float* __restrict__ zguard, void* __restrict__ outv) {
    constexpr int CIN = ICG * 8;
    constexpr int NCH = 24 * ICG * 34;             // 16 B chunks (4x6 cols)
    __shared__ short lds[NCH * 8];
    // XCD swizzle: contiguous slab per XCD
    int wg = ((blockIdx.x & 7) << 8) | (blockIdx.x >> 3);   // 2048
    int zh = wg & 1, yq = (wg >> 1) & 15, xp = (wg >> 5) & 31, b = wg >> 10;
    int X0 = xp * 2, Y0 = yq * 4, Z0 = zh * 32;
    int tid = threadIdx.x;

    const ushortT* inb = in + (size_t)b * (64 * 64 * 64 * CIN);
#pragma unroll
    for (int it = 0; it < (NCH + 255) / 256; ++it) {
        int ccid = it * 256 + tid;
        if (ccid < NCH) {
            int col = ccid / (ICG * 34);
            int rem = ccid - col * (ICG * 34);
            int icg = rem / 34;
            int zi  = rem - icg * 34;
            int gx = X0 + col / 6 - 1;
            int gy = Y0 + col % 6 - 1;
            int gz = Z0 + zi - 1;
            const void* src = (const void*)zguard;
            if ((unsigned)gx < 64u && (unsigned)gy < 64u && (unsigned)gz < 64u)
                src = (const void*)(inb + ((size_t)(((gx * 64) + gy) * 64 + gz)) * CIN + icg * 8);
            load_lds16(src, (void*)(lds + ccid * 8));
        }
    }
    __syncthreads();   // drains vmcnt (global_load_lds) + barrier

    int l = tid & 63, w = tid >> 6;
    int wx = w >> 1;                               // owned x in 2
    int cyA = (w & 1) * 2, cyB = cyA + 1;          // owned y pair in 4
    int n = l & 31, q = l >> 5;

    float bval = FINAL ? (n < 4 ? bias[n] : 0.f) : bias[n];
    float16 accA, accB;
#pragma unroll
    for (int r = 0; r < 16; ++r) { accA[r] = bval; accB[r] = bval; }

    const short* bp = Bpack + (size_t)l * 8;
    int laneZ = (l & 31) * 8;                      // z-row offset (shorts)

    short8 bf[4];
#pragma unroll
    for (int i = 0; i < 4; ++i) bf[i] = *(const short8*)(bp + i * 512);

#pragma unroll
    for (int kt = 0; kt < KT; ++kt) {
        short8 bcur = bf[kt & 3];
        if (kt + 4 < KT) bf[kt & 3] = *(const short8*)(bp + (kt + 4) * 512);
        int aofsA, aofsB;
        if constexpr (ICG == 1) {
            int tap0 = kt * 2, tap1 = kt * 2 + 1;
            if (tap1 > 26) tap1 = 26;              // B is zero there
            int dx0 = tap0 / 9, r0 = tap0 - dx0 * 9, dy0 = r0 / 3, dz0 = r0 - dy0 * 3;
            int dx1 = tap1 / 9, r1 = tap1 - dx1 * 9, dy1 = r1 / 3, dz1 = r1 - dy1 * 3;
            int cA0 = (((wx + dx0) * 6 + (cyA + dy0)) * 34 + dz0) * 8;
            int cA1 = (((wx + dx1) * 6 + (cyA + dy1)) * 34 + dz1) * 8;
            int cB0 = (((wx + dx0) * 6 + (cyB + dy0)) * 34 + dz0) * 8;
            int cB1 = (((wx + dx1) * 6 + (cyB + dy1)) * 34 + dz1) * 8;
            aofsA = q ? cA1 : cA0;
            aofsB = q ? cB1 : cB0;
        } else {
            int tap = kt >> 1;
            int dx = tap / 9, rr = tap - dx * 9, dy = rr / 3, dz = rr - dy * 3;
            int icg = (kt & 1) * 2 + q;
            aofsA = ((((wx + dx) * 6 + (cyA + dy)) * ICG + icg) * 34 + dz) * 8;
            aofsB = ((((wx + dx) * 6 + (cyB + dy)) * ICG + icg) * 34 + dz) * 8;
        }
        short8 afragA = *(const short8*)(lds + aofsA + laneZ);
        short8 afragB = *(const short8*)(lds + aofsB + laneZ);
        accA = __builtin_amdgcn_mfma_f32_32x32x16_bf16(afragA, bcur, accA, 0, 0, 0);
        accB = __builtin_amdgcn_mfma_f32_32x32x16_bf16(afragB, bcur, accB, 0, 0, 0);
    }

    size_t baseA = (size_t)(((b * 64 + X0 + wx) * 64 + (Y0 + cyA)) * 64) + Z0;
    size_t baseB = (size_t)(((b * 64 + X0 + wx) * 64 + (Y0 + cyB)) * 64) + Z0;
    if (FINAL) {
        float* out = (float*)outv;
        if (n < 4) {
#pragma unroll
            for (int r = 0; r < 16; ++r) {
                int z = (r & 3) + 8 * (r >> 2) + 4 * q;
                out[(baseA + z) * 4 + n] = accA[r];
                out[(baseB + z) * 4 + n] = accB[r];
            }
        }
    } else {
        float a = alpha[0];
        ushortT* out = (ushortT*)outv;
#pragma unroll
        for (int r = 0; r < 16; ++r) {
            int z = (r & 3) + 8 * (r >> 2) + 4 * q;
            float vA = accA[r];
            vA = vA >= 0.f ? vA : a * vA;
            out[(baseA + z) * 32 + n] = bf16_rne(vA);
            float vB = accB[r];
            vB = vB >= 0.f ? vB : a * vB;
            out[(baseB + z) * 32 + n] = bf16_rne(vB);
        }
    }
}

// ---------------- grid2particles (trilinear gather, fp32 grid) ----------------
__global__ __launch_bounds__(256) void gather_kernel(
    const float* __restrict__ grid, const float* __restrict__ locs,
    float* __restrict__ out) {
    int t = blockIdx.x * blockDim.x + threadIdx.x;
    if (t >= BATCH * NPART) return;
    int b = t >> 15;

    float px = locs[t * 3 + 0] * 64.0f - 0.5f;
    float py = locs[t * 3 + 1] * 64.0f - 0.5f;
    float pz = locs[t * 3 + 2] * 64.0f - 0.5f;
    int ix = (int)floorf(px);
    int iy = (int)floorf(py);
    int iz = (int)floorf(pz);
    float fx = px - (float)ix;
    float fy = py - (float)iy;
    float fz = pz - (float)iz;

    const float* gb = grid + (size_t)b * GD * GD * GD * 4;
    float o0 = 0.f, o1 = 0.f, o2 = 0.f, o3 = 0.f;

#pragma unroll
    for (int dx = 0; dx < 2; ++dx) {
        int x = ix + dx;
        if ((unsigned)x > 63u) continue;
        float wx = dx ? fx : 1.0f - fx;
#pragma unroll
        for (int dy = 0; dy < 2; ++dy) {
            int y = iy + dy;
            if ((unsigned)y > 63u) continue;
            float wy = dy ? fy : 1.0f - fy;
#pragma unroll
            for (int dz = 0; dz < 2; ++dz) {
                int z = iz + dz;
                if ((unsigned)z > 63u) continue;
                float wz = dz ? fz : 1.0f - fz;
                float w = wx * wy * wz;
                const float4 g = *(const float4*)(gb + (size_t)(((x * GD) + y) * GD + z) * 4);
                o0 += w * g.x; o1 += w * g.y; o2 += w * g.z; o3 += w * g.w;
            }
        }
    }
    out[t * 4 + 0] = o0;
    out[t * 4 + 1] = o1;
    out[t * 4 + 2] = o2;
    out[t * 4 + 3] = o3;
}

extern "C" void kernel_launch(void* const* d_in, const int* in_sizes, int n_in,
                              void* d_out, int out_size, void* d_ws, size_t ws_size,
                              hipStream_t stream) {
    const float* locs    = (const float*)d_in[0];
    const float* data    = (const float*)d_in[1];
    const float* density = (const float*)d_in[2];
    const float* W0 = (const float*)d_in[3];
    const float* b0 = (const float*)d_in[4];
    const float* W1 = (const float*)d_in[5];
    const float* b1 = (const float*)d_in[6];
    const float* W2 = (const float*)d_in[7];
    const float* b2 = (const float*)d_in[8];
    const float* W3 = (const float*)d_in[9];
    const float* b3 = (const float*)d_in[10];
    const float* a0 = (const float*)d_in[11];
    const float* a1 = (const float*)d_in[12];
    const float* a2 = (const float*)d_in[13];
    float* out = (float*)d_out;

    char* ws = (char*)d_ws;
    ushortT* g8  = (ushortT*)(ws);                       // 8 MB bf16 8ch
    ushortT* gA  = (ushortT*)(ws + 8388608);             // 33.5 MB bf16 32ch
    ushortT* gB  = (ushortT*)(ws + 41943040);            // 33.5 MB bf16 32ch
    float*  gF   = (float*)(ws + 75497472);              // 8 MB fp32 4ch
    short*  Bp   = (short*)(ws + 83886080);              // 176*512*2 = 180224 B
    short*  Bp0  = Bp;                                   // kt 0..13
    short*  Bp1  = Bp + 14 * 512;                        // kt 14..67
    short*  Bp2  = Bp + 68 * 512;                        // kt 68..121
    short*  Bp3  = Bp + 122 * 512;                       // kt 122..175
    float* zguard   = (float*)(ws + 84066240);           // 64 B zeros (16 ints)
    int*   counts   = (int*)(ws + 84066304);             // 65536 ints
    int*   cursor   = (int*)(ws + 84328448);             // 65536 ints
    int*   offsets  = (int*)(ws + 84590592);             // 65537 ints
    int*   blockSum = (int*)(ws + 84852752);             // 256 ints
    float* payload  = (float*)(ws + 84853888);           // 65536*8 floats = 2 MB

    // ---- zero zguard + counts + cursor (contiguous from zguard) ----
    zero_ints_kernel<<<(131088 + 255) / 256, 256, 0, stream>>>((int*)zguard, 131088);
    bin_count_kernel<<<(BATCH * NPART) / 256, 256, 0, stream>>>(locs, counts);
    scanA_kernel<<<256, 256, 0, stream>>>(counts, offsets, blockSum);
    scanB_kernel<<<256, 256, 0, stream>>>(offsets, blockSum);
    bin_scatter_kernel<<<(BATCH * NPART) / 256, 256, 0, stream>>>(
        locs, data, density, offsets, cursor, payload);

    // ---- weight repack (fused) ----
    repack_all_kernel<<<(176 * 512 + 255) / 256, 256, 0, stream>>>(W0, W1, W2, W3, Bp);

    // ---- particles -> bf16 grid (cell-owner gather, no atomics) ----
    splat_gather_kernel<<<BATCH * 512, 256, 0, stream>>>(payload, offsets, g8);

    // ---- conv chain ----
    const int CGRID = 2048;   // 2 b x 32 xp x 16 yq x 2 zh
    mfma_conv_kernel< 1, 14, false><<<CGRID, 256, 0, stream>>>(g8, Bp0, b0, a0, zguard, gA);
    mfma_conv_kernel< 4, 54, false><<<CGRID, 256, 0, stream>>>(gA, Bp1, b1, a1, zguard, gB);
    mfma_conv_kernel< 4, 54, false><<<CGRID, 256, 0, stream>>>(gB, Bp2, b2, a2, zguard, gA);
    mfma_conv_kernel< 4, 54, true ><<<CGRID, 256, 0, stream>>>(gA, Bp3, b3, b3, zguard, gF);

    // ---- grid -> particles ----
    gather_kernel<<<(BATCH * NPART) / 256, 256, 0, stream>>>(gF, locs, out);
}